// Round 15
// baseline (807.688 us; speedup 1.0000x reference)
//
#include <hip/hip_runtime.h>

// DescrptDPA1 on gfx950 — R15: R14 + (a) 2-pass K/V jobs (norm pass, then
// recompute+scaled-store pass — deletes kv/vv[8][4] live arrays, kills the
// residual spill) and (b) native amdgpu_waves_per_eu(4,4) attribute pair.
// NF=1, NLOC=4096, NNEI=120, TEBD=8, NTYPES=4, M=100, ATTN=128, NLAYER=2, AXIS=16.

#define NNEI 120
#define MDIM 100
#define ADIM 128
#define BP   136   // bf16 pitch (272B rows; 68 dw = 4 mod 32 banks, 16B aligned)
#define H2P  72    // bf16 pitch for h2 staging
#define XP   40    // bf16 pitch for x / h1 staging (80B rows, 16B aligned)
#define OUTD 1608

typedef __attribute__((ext_vector_type(8))) short bf16x8;
typedef __attribute__((ext_vector_type(4))) float f32x4;

__device__ __forceinline__ float bf2f(unsigned short u){
    return __uint_as_float(((unsigned int)u) << 16);
}
__device__ __forceinline__ unsigned short f2bf(float f){
    unsigned int x = __float_as_uint(f);
    return (unsigned short)((x + 0x7fffu + ((x >> 16) & 1u)) >> 16);
}
__device__ __forceinline__ unsigned int cvtpk(float lo, float hi){
    unsigned int r;
    asm("v_cvt_pk_bf16_f32 %0, %1, %2" : "=v"(r) : "v"(lo), "v"(hi));
    return r;
}
__device__ __forceinline__ float ftanh(float x){
    return 1.0f - 2.0f / (__expf(2.0f * x) + 1.0f);
}
__device__ __forceinline__ float red16(float v){
    v += __shfl_xor(v, 1, 64); v += __shfl_xor(v, 2, 64);
    v += __shfl_xor(v, 4, 64); v += __shfl_xor(v, 8, 64);
    return v;
}

// nmask storage detection: 1 = int32 {0,1}, 2 = f32 {0.0,1.0}, 0 = byte bool
__global__ void detect_mask_kernel(const unsigned char* __restrict__ p,
                                   int* __restrict__ flag){
    if (blockIdx.x == 0 && threadIdx.x == 0){
        const unsigned int* u = (const unsigned int*)p;
        int alli = 1, allf = 1;
        for (int i = 0; i < 64; ++i){
            unsigned int w = u[i];
            if (!(w == 0u || w == 1u)) alli = 0;
            if (!(w == 0u || w == 0x3f800000u)) allf = 0;
        }
        flag[0] = alli ? 1 : (allf ? 2 : 0);
    }
}

// Pack weights (bf16). Frag = [64 lanes][8 bf16] = 1024B.
// QKV B-frags: fid = ((l*3+mat)*8+nt)*4+ks            (0..191)
// WO A-frags:  fid = 192 + (l*8+jt)*4+ks              (192..255, jt=7 zero)
// ew2 B-frags: fid = 256 + nt*2 + ks                  (256..269)
// ew0 B-frags: fid = 270 + nt   (nt=0,1; K=17 pad 32) (270..271)
// ew1 B-frags: fid = 272 + nt   (nt=0..3; K=25 pad 32)(272..275)
__global__ void prep_weights(const float* __restrict__ wq, const float* __restrict__ wk,
                             const float* __restrict__ wv, const float* __restrict__ wo,
                             const float* __restrict__ ew2, const float* __restrict__ ew0,
                             const float* __restrict__ ew1,
                             unsigned short* __restrict__ wsb){
    const int fid = blockIdx.x;
    const int lane = threadIdx.x;  // 64
    unsigned short* dst = wsb + (size_t)fid * 512 + lane * 8;
    if (fid < 192){
        const int l = fid / 96, rem = fid % 96, mat = rem / 32;
        const int r2 = rem % 32, nt = r2 / 4, ks = r2 % 4;
        const float* W = (mat == 0 ? wq : mat == 1 ? wk : wv) + l * MDIM * ADIM;
        const int nn = nt * 16 + (lane & 15);
        const int k0 = ks * 32 + (lane >> 4) * 8;
        #pragma unroll
        for (int i = 0; i < 8; ++i){
            const int kk = k0 + i;
            dst[i] = (kk < MDIM) ? f2bf(W[kk * ADIM + nn]) : (unsigned short)0;
        }
    } else if (fid < 256){
        const int f2 = fid - 192, l = f2 / 32, rem = f2 % 32, jt = rem / 4, ks = rem % 4;
        const float* W = wo + l * ADIM * MDIM;
        const int j = jt * 16 + (lane & 15);
        const int d0 = ks * 32 + (lane >> 4) * 8;
        #pragma unroll
        for (int i = 0; i < 8; ++i)
            dst[i] = (j < MDIM) ? f2bf(W[(d0 + i) * MDIM + j]) : (unsigned short)0;
    } else if (fid < 270){
        const int f3 = fid - 256, nt = f3 >> 1, ks = f3 & 1;
        const int nn = nt * 16 + (lane & 15);
        const int k0 = ks * 32 + (lane >> 4) * 8;
        #pragma unroll
        for (int i = 0; i < 8; ++i){
            const int kk = k0 + i;
            dst[i] = (kk < 50 && nn < MDIM) ? f2bf(ew2[kk * MDIM + nn]) : (unsigned short)0;
        }
    } else if (fid < 272){
        const int nt = fid - 270;
        const int nn = nt * 16 + (lane & 15);
        const int k0 = (lane >> 4) * 8;
        #pragma unroll
        for (int i = 0; i < 8; ++i){
            const int kk = k0 + i;
            dst[i] = (kk < 17 && nn < 25) ? f2bf(ew0[kk * 25 + nn]) : (unsigned short)0;
        }
    } else {
        const int nt = fid - 272;
        const int nn = nt * 16 + (lane & 15);
        const int k0 = (lane >> 4) * 8;
        #pragma unroll
        for (int i = 0; i < 8; ++i){
            const int kk = k0 + i;
            dst[i] = (kk < 25 && nn < 50) ? f2bf(ew1[kk * 50 + nn]) : (unsigned short)0;
        }
    }
}

__global__
__attribute__((amdgpu_flat_work_group_size(1024, 1024), amdgpu_waves_per_eu(4, 4)))
void dpa1_kernel(
    const float* __restrict__ rij, const void* __restrict__ nmask,
    const int* __restrict__ atype, const int* __restrict__ ntype,
    const float* __restrict__ tebd,
    const float* __restrict__ eb0, const float* __restrict__ eb1,
    const float* __restrict__ eb2,
    const float* __restrict__ bq, const float* __restrict__ bk,
    const float* __restrict__ bv, const float* __restrict__ bo,
    const float* __restrict__ lng, const float* __restrict__ lnb,
    float* __restrict__ out, const int* __restrict__ flagp,
    const unsigned short* __restrict__ wsb)
{
    __shared__ __align__(16) unsigned short g16[128 * BP];   // bf16 g master
    __shared__ __align__(16) unsigned short buf1[128 * BP];  // h2 -> Qraw -> P~
    __shared__ __align__(16) unsigned short kn_s[128 * BP];  // x -> Kn -> O'
    __shared__ __align__(16) unsigned short vT_s[128 * BP];  // h1 -> Vn^T
    __shared__ float psum_s[256];
    __shared__ float lnp_s[512];
    __shared__ float qss_s[128];          // |Q row|^2 accumulators
    __shared__ __align__(16) float env_s[128 * 4];
    __shared__ __align__(16) float rhat_s[128 * 4];
    __shared__ __align__(16) float swm_s[128];
    __shared__ __align__(16) float msk_s[128];
    __shared__ float tebd_s[32];
    __shared__ float gr_s[4 * MDIM];
    __shared__ int ta_sh;

    const int n    = blockIdx.x;
    const int tid  = threadIdx.x;
    const int lane = tid & 63;
    const int wid  = tid >> 6;
    const int flag = flagp[0];
    const int l15  = lane & 15;
    const int lg4  = lane >> 4;

    if (tid < 32) tebd_s[tid] = tebd[tid];
    if (tid == 0) ta_sh = atype[n];

    // ---------------- P-geom: geometry + x staging + zero g16 ----------------
    {
        unsigned int* z0 = (unsigned int*)g16;
        for (int i = tid; i < 128 * (BP/2); i += 1024) z0[i] = 0;
    }
    if (tid < 128){
        const int k = tid;
        unsigned short xr[2 * XP];
        #pragma unroll
        for (int i = 0; i < 2 * XP; ++i) xr[i] = 0;
        if (k < NNEI){
            const int base = n * NNEI + k;
            const float rx = rij[base * 3 + 0];
            const float ry = rij[base * 3 + 1];
            const float rz = rij[base * 3 + 2];
            const float r  = sqrtf(rx * rx + ry * ry + rz * rz);
            float mval;
            if (flag == 1)      mval = (((const int*)nmask)[base] != 0) ? 1.0f : 0.0f;
            else if (flag == 2) mval = ((const float*)nmask)[base];
            else                mval = (((const unsigned char*)nmask)[base] != 0) ? 1.0f : 0.0f;
            float uu = (r - 0.5f) * (1.0f / 5.5f);
            uu = fminf(fmaxf(uu, 0.0f), 1.0f);
            const float sw   = uu * uu * uu * (-6.0f * uu * uu + 15.0f * uu - 10.0f) + 1.0f;
            const float invr = 1.0f / r;
            const float sr   = sw * invr * mval;
            const float hx = rx * invr, hy = ry * invr, hz = rz * invr;
            env_s[k * 4 + 0] = sr;
            env_s[k * 4 + 1] = sr * hx;
            env_s[k * 4 + 2] = sr * hy;
            env_s[k * 4 + 3] = sr * hz;
            rhat_s[k * 4 + 0] = hx; rhat_s[k * 4 + 1] = hy; rhat_s[k * 4 + 2] = hz;
            rhat_s[k * 4 + 3] = 0.0f;
            swm_s[k] = sw * mval;
            msk_s[k] = mval;
            const int tn = ntype[base] * 8;
            const int tc = atype[n] * 8;
            xr[0] = f2bf(sr);
            #pragma unroll
            for (int i = 0; i < 8; ++i){
                xr[1 + i] = f2bf(tebd[tn + i]);
                xr[9 + i] = f2bf(tebd[tc + i]);
            }
        } else {
            env_s[k*4+0] = env_s[k*4+1] = env_s[k*4+2] = env_s[k*4+3] = 0.0f;
            rhat_s[k*4+0] = rhat_s[k*4+1] = rhat_s[k*4+2] = rhat_s[k*4+3] = 0.0f;
            swm_s[k] = 0.0f; msk_s[k] = 0.0f;
        }
        #pragma unroll
        for (int c = 0; c < 5; ++c)
            *(uint4*)&kn_s[k * XP + c * 8] = *(const uint4*)&xr[c * 8];
    }
    __syncthreads();

    // ---------------- e1 (MFMA): h1 = tanh(x @ ew0 + eb0) -> vT_s bf16 -------
    {
        const int mt = wid >> 1, nt = wid & 1;   // 16 jobs, 1 per wave
        bf16x8 a = *(const bf16x8*)&kn_s[(mt*16 + l15) * XP + lg4 * 8];
        bf16x8 b = *(const bf16x8*)(wsb + (size_t)(270 + nt) * 512 + lane * 8);
        f32x4 C = (f32x4){0.f, 0.f, 0.f, 0.f};
        C = __builtin_amdgcn_mfma_f32_16x16x32_bf16(a, b, C, 0, 0, 0);
        const int j = nt * 16 + l15;
        const float ebj = (j < 25) ? eb0[j] : 0.0f;
        #pragma unroll
        for (int r = 0; r < 4; ++r){
            const int row = mt * 16 + lg4 * 4 + r;
            const float v = (row < NNEI && j < 25) ? ftanh(C[r] + ebj) : 0.0f;
            vT_s[row * XP + j] = f2bf(v);
        }
    }
    __syncthreads();

    // ---------------- e2 (MFMA): h2 = tanh(h1 @ ew1 + eb1) + [h1,h1] -> buf1 --
    {
        for (int jb = wid; jb < 32; jb += 16){   // 2 jobs per wave
            const int mt = jb >> 2, nt = jb & 3;
            bf16x8 a = *(const bf16x8*)&vT_s[(mt*16 + l15) * XP + lg4 * 8];
            bf16x8 b = *(const bf16x8*)(wsb + (size_t)(272 + nt) * 512 + lane * 8);
            f32x4 C = (f32x4){0.f, 0.f, 0.f, 0.f};
            C = __builtin_amdgcn_mfma_f32_16x16x32_bf16(a, b, C, 0, 0, 0);
            const int j2 = nt * 16 + l15;
            const float ebj = (j2 < 50) ? eb1[j2] : 0.0f;
            const int jr = (j2 >= 25) ? j2 - 25 : j2;
            #pragma unroll
            for (int r = 0; r < 4; ++r){
                const int row = mt * 16 + lg4 * 4 + r;
                float v = 0.0f;
                if (row < NNEI && j2 < 50){
                    const float h1d = bf2f(vT_s[row * XP + jr]);
                    v = ftanh(C[r] + ebj) + h1d;
                }
                buf1[row * H2P + j2] = f2bf(v);
            }
        }
    }
    __syncthreads();

    // ---------------- e3: g = (tanh(h2 @ ew2 + eb2) + [h2,h2]) * m  (MFMA) ---
    {
        for (int job = wid; job < 56; job += 16){
            const int mt = job / 7, nt = job - mt * 7;
            bf16x8 a0 = *(const bf16x8*)&buf1[(mt*16 + l15) * H2P + 0*32 + lg4 * 8];
            bf16x8 a1 = *(const bf16x8*)&buf1[(mt*16 + l15) * H2P + 1*32 + lg4 * 8];
            bf16x8 b0 = *(const bf16x8*)(wsb + (size_t)(256 + nt*2 + 0) * 512 + lane * 8);
            bf16x8 b1 = *(const bf16x8*)(wsb + (size_t)(256 + nt*2 + 1) * 512 + lane * 8);
            f32x4 C = (f32x4){0.f, 0.f, 0.f, 0.f};
            C = __builtin_amdgcn_mfma_f32_16x16x32_bf16(a0, b0, C, 0, 0, 0);
            C = __builtin_amdgcn_mfma_f32_16x16x32_bf16(a1, b1, C, 0, 0, 0);
            const int j = nt * 16 + l15;
            if (j < MDIM){
                const float ebj = eb2[j];
                const int jr = (j >= 50) ? j - 50 : j;
                #pragma unroll
                for (int r = 0; r < 4; ++r){
                    const int row = mt * 16 + lg4 * 4 + r;
                    if (row < NNEI){
                        const float h2d = bf2f(buf1[row * H2P + jr]);
                        const float t = ftanh(C[r] + ebj) + h2d;
                        g16[row * BP + j] = f2bf(t * msk_s[row]);
                    }
                }
            }
        }
        if (tid < 128) qss_s[tid] = 0.0f;
    }
    __syncthreads();

    // ---------------- Attention layers ----------------
    const float tinv = 0.08838834764831845f;  // 1/sqrt(128)
    const int qt = wid >> 1;   // core pair: q-tile
    const int hh = wid & 1;    // core pair: half index
    const int q  = qt * 16 + l15;

    for (int l = 0; l < 2; ++l){
        // ===== A1 (balanced, 2-pass K/V): each wave = 1 full K-or-V job
        //       (pass1 norms, pass2 recompute+scaled store) + 1 half Q job ====
        {
            const int t = wid & 7;
            bf16x8 ag[4];
            #pragma unroll
            for (int ks = 0; ks < 4; ++ks)
                ag[ks] = *(const bf16x8*)&g16[(t*16 + l15) * BP + ks*32 + lg4 * 8];
            if (wid < 8){
                // K tile t, pass 1: row sum-squares only
                float sq[4] = {0.f, 0.f, 0.f, 0.f};
                #pragma unroll
                for (int nt = 0; nt < 8; ++nt){
                    f32x4 C = (f32x4){0.f, 0.f, 0.f, 0.f};
                    #pragma unroll
                    for (int ks = 0; ks < 4; ++ks){
                        bf16x8 b = *(const bf16x8*)(wsb + (size_t)(((l*3+1)*8+nt)*4+ks) * 512 + lane * 8);
                        C = __builtin_amdgcn_mfma_f32_16x16x32_bf16(ag[ks], b, C, 0, 0, 0);
                    }
                    const float bias = bk[l * ADIM + nt*16 + l15];
                    #pragma unroll
                    for (int r = 0; r < 4; ++r){
                        const float v = C[r] + bias;
                        sq[r] = fmaf(v, v, sq[r]);
                    }
                }
                float kss[4];
                #pragma unroll
                for (int r = 0; r < 4; ++r)
                    kss[r] = tinv * rsqrtf(fmaxf(red16(sq[r]), 1e-24f));
                // pass 2: recompute + scaled store
                #pragma unroll
                for (int nt = 0; nt < 8; ++nt){
                    f32x4 C = (f32x4){0.f, 0.f, 0.f, 0.f};
                    #pragma unroll
                    for (int ks = 0; ks < 4; ++ks){
                        bf16x8 b = *(const bf16x8*)(wsb + (size_t)(((l*3+1)*8+nt)*4+ks) * 512 + lane * 8);
                        C = __builtin_amdgcn_mfma_f32_16x16x32_bf16(ag[ks], b, C, 0, 0, 0);
                    }
                    const float bias = bk[l * ADIM + nt*16 + l15];
                    #pragma unroll
                    for (int r = 0; r < 4; ++r)
                        kn_s[(t*16 + lg4*4 + r) * BP + nt*16 + l15] = f2bf((C[r] + bias) * kss[r]);
                }
            } else {
                // V tile t, pass 1: row sum-squares only
                float sq[4] = {0.f, 0.f, 0.f, 0.f};
                #pragma unroll
                for (int nt = 0; nt < 8; ++nt){
                    f32x4 C = (f32x4){0.f, 0.f, 0.f, 0.f};
                    #pragma unroll
                    for (int ks = 0; ks < 4; ++ks){
                        bf16x8 b = *(const bf16x8*)(wsb + (size_t)(((l*3+2)*8+nt)*4+ks) * 512 + lane * 8);
                        C = __builtin_amdgcn_mfma_f32_16x16x32_bf16(ag[ks], b, C, 0, 0, 0);
                    }
                    const float bias = bv[l * ADIM + nt*16 + l15];
                    #pragma unroll
                    for (int r = 0; r < 4; ++r){
                        const float v = C[r] + bias;
                        sq[r] = fmaf(v, v, sq[r]);
                    }
                }
                float vs[4];
                #pragma unroll
                for (int r = 0; r < 4; ++r){
                    const int k = t*16 + lg4*4 + r;
                    vs[r] = swm_s[k] * rsqrtf(fmaxf(red16(sq[r]), 1e-24f));
                }
                // pass 2: recompute + scaled transposed store
                #pragma unroll
                for (int nt = 0; nt < 8; ++nt){
                    f32x4 C = (f32x4){0.f, 0.f, 0.f, 0.f};
                    #pragma unroll
                    for (int ks = 0; ks < 4; ++ks){
                        bf16x8 b = *(const bf16x8*)(wsb + (size_t)(((l*3+2)*8+nt)*4+ks) * 512 + lane * 8);
                        C = __builtin_amdgcn_mfma_f32_16x16x32_bf16(ag[ks], b, C, 0, 0, 0);
                    }
                    const float bias = bv[l * ADIM + nt*16 + l15];
                    const unsigned int lo = cvtpk((C[0] + bias) * vs[0], (C[1] + bias) * vs[1]);
                    const unsigned int hi = cvtpk((C[2] + bias) * vs[2], (C[3] + bias) * vs[3]);
                    *(uint2*)&vT_s[(nt*16 + l15) * BP + t*16 + lg4*4] = make_uint2(lo, hi);
                }
            }
            __builtin_amdgcn_sched_barrier(0);
            // Half-width raw-Q job on the SAME tile t, half hq = wid>>3
            {
                const int hq = wid >> 3;
                float sq2[4] = {0.f, 0.f, 0.f, 0.f};
                #pragma unroll
                for (int u = 0; u < 4; ++u){
                    const int nt = hq*4 + u;
                    f32x4 C = (f32x4){0.f, 0.f, 0.f, 0.f};
                    #pragma unroll
                    for (int ks = 0; ks < 4; ++ks){
                        bf16x8 b = *(const bf16x8*)(wsb + (size_t)(((l*3+0)*8+nt)*4+ks) * 512 + lane * 8);
                        C = __builtin_amdgcn_mfma_f32_16x16x32_bf16(ag[ks], b, C, 0, 0, 0);
                    }
                    const float bias = bq[l * ADIM + nt*16 + l15];
                    #pragma unroll
                    for (int r = 0; r < 4; ++r){
                        const float v = C[r] + bias;
                        buf1[(t*16 + lg4*4 + r) * BP + nt*16 + l15] = f2bf(v);
                        sq2[r] = fmaf(v, v, sq2[r]);
                    }
                }
                #pragma unroll
                for (int r = 0; r < 4; ++r){
                    const float s = red16(sq2[r]);
                    if (l15 == 0) atomicAdd(&qss_s[t*16 + lg4*4 + r], s);
                }
            }
        }
        __syncthreads();  // B1: Qraw, Kn, Vn^T, qss ready

        // ===== Core1: scores half (wave pair qt,hh) =====
        unsigned int pw0[4], pw1[4];
        float tot;
        {
            bf16x8 bqf[4];
            #pragma unroll
            for (int ks = 0; ks < 4; ++ks)
                bqf[ks] = *(const bf16x8*)&buf1[(qt*16 + l15) * BP + ks*32 + lg4 * 8];
            f32x4 Cs[4];
            #pragma unroll
            for (int t = 0; t < 4; ++t) Cs[t] = (f32x4){0.f, 0.f, 0.f, 0.f};
            #pragma unroll
            for (int t = 0; t < 4; ++t)
                #pragma unroll
                for (int ks = 0; ks < 4; ++ks){
                    bf16x8 a = *(const bf16x8*)&kn_s[((hh*4+t)*16 + l15) * BP + ks*32 + lg4 * 8];
                    Cs[t] = __builtin_amdgcn_mfma_f32_16x16x32_bf16(a, bqf[ks], Cs[t], 0, 0, 0);
                }
            const float qi = rsqrtf(fmaxf(qss_s[q], 1e-24f));
            const float4 rq = *(const float4*)&rhat_s[q * 4];
            tot = 0.f;
            #pragma unroll
            for (int t = 0; t < 4; ++t){
                const int kb = (hh*4+t)*16 + lg4*4;
                float p[4];
                #pragma unroll
                for (int r = 0; r < 4; ++r){
                    const float e = __expf(Cs[t][r] * qi) * msk_s[kb + r];
                    tot += e;
                    const float4 rk = *(const float4*)&rhat_s[(kb + r) * 4];
                    p[r] = e * (rq.x*rk.x + rq.y*rk.y + rq.z*rk.z);
                }
                pw0[t] = cvtpk(p[0], p[1]);
                pw1[t] = cvtpk(p[2], p[3]);
            }
            tot += __shfl_xor(tot, 16, 64);
            tot += __shfl_xor(tot, 32, 64);
        }
        __syncthreads();  // B2: all Q/K reads done; buf1/kn rows reusable

        // ===== Core2: publish P~ (= e*gate) and psum =====
        #pragma unroll
        for (int t = 0; t < 4; ++t)
            *(uint2*)&buf1[(qt*16 + l15) * BP + (hh*4+t)*16 + lg4*4] = make_uint2(pw0[t], pw1[t]);
        if (lg4 == 0) psum_s[q * 2 + hh] = tot;
        __syncthreads();  // B3: P~, psum visible

        // ===== Core3: PV half; apply rsum to O'; publish O' =====
        {
            bf16x8 bpf[4];
            #pragma unroll
            for (int ks = 0; ks < 4; ++ks)
                bpf[ks] = *(const bf16x8*)&buf1[(qt*16 + l15) * BP + ks*32 + lg4 * 8];
            f32x4 Co[4];
            #pragma unroll
            for (int t = 0; t < 4; ++t) Co[t] = (f32x4){0.f, 0.f, 0.f, 0.f};
            #pragma unroll
            for (int t = 0; t < 4; ++t)
                #pragma unroll
                for (int ks = 0; ks < 4; ++ks){
                    bf16x8 a = *(const bf16x8*)&vT_s[((hh*4+t)*16 + l15) * BP + ks*32 + lg4 * 8];
                    Co[t] = __builtin_amdgcn_mfma_f32_16x16x32_bf16(a, bpf[ks], Co[t], 0, 0, 0);
                }
            const float totq = psum_s[q * 2] + psum_s[q * 2 + 1];
            const float rsum = (totq > 0.0f) ? swm_s[q] / totq : 0.0f;
            #pragma unroll
            for (int t = 0; t < 4; ++t){
                const unsigned int lo = cvtpk(Co[t][0] * rsum, Co[t][1] * rsum);
                const unsigned int hi = cvtpk(Co[t][2] * rsum, Co[t][3] * rsum);
                *(uint2*)&kn_s[(qt*16 + l15) * BP + (hh*4+t)*16 + lg4*4] = make_uint2(lo, hi);
            }
        }
        __syncthreads();  // B4: O' visible

        // ===== Core4: out-proj half + LN partials =====
        float val[4][4];
        {
            bf16x8 bof[4];
            #pragma unroll
            for (int ks = 0; ks < 4; ++ks)
                bof[ks] = *(const bf16x8*)&kn_s[(qt*16 + l15) * BP + ks*32 + lg4 * 8];
            const float* BO = bo + l * MDIM;
            float sv = 0.f, sv2 = 0.f;
            #pragma unroll
            for (int t = 0; t < 4; ++t){
                const int jt = hh*4 + t;
                f32x4 Cf = (f32x4){0.f, 0.f, 0.f, 0.f};
                #pragma unroll
                for (int ks = 0; ks < 4; ++ks){
                    bf16x8 a = *(const bf16x8*)(wsb + (size_t)(192 + (l*8+jt)*4 + ks) * 512 + lane * 8);
                    Cf = __builtin_amdgcn_mfma_f32_16x16x32_bf16(a, bof[ks], Cf, 0, 0, 0);
                }
                const bool jok = (jt < 6) || (jt == 6 && lg4 == 0);
                float4 BO4 = jok ? *(const float4*)&BO[jt*16 + lg4*4] : make_float4(0,0,0,0);
                #pragma unroll
                for (int r = 0; r < 4; ++r){
                    const float v = Cf[r] + ((const float*)&BO4)[r];
                    val[t][r] = v;
                    if (jok){ sv += v; sv2 += v * v; }
                }
            }
            sv  += __shfl_xor(sv, 16, 64);  sv  += __shfl_xor(sv, 32, 64);
            sv2 += __shfl_xor(sv2, 16, 64); sv2 += __shfl_xor(sv2, 32, 64);
            if (lg4 == 0){
                lnp_s[q * 4 + hh * 2 + 0] = sv;
                lnp_s[q * 4 + hh * 2 + 1] = sv2;
            }
        }
        __syncthreads();  // B5: LN partials visible

        // ===== Core5: LayerNorm apply + residual into g16 (own jt half) =====
        {
            const float* LG = lng + l * MDIM;
            const float* LB = lnb + l * MDIM;
            const float svt  = lnp_s[q * 4 + 0] + lnp_s[q * 4 + 2];
            const float sv2t = lnp_s[q * 4 + 1] + lnp_s[q * 4 + 3];
            const float mu   = svt * 0.01f;
            const float var  = sv2t * 0.01f - mu * mu;
            const float rstd = rsqrtf(var + 1e-5f);
            if (q < NNEI){
                #pragma unroll
                for (int t = 0; t < 4; ++t){
                    const int jt = hh*4 + t;
                    const bool jok = (jt < 6) || (jt == 6 && lg4 == 0);
                    if (jok){
                        const int jb = jt*16 + lg4*4;
                        const float4 LG4 = *(const float4*)&LG[jb];
                        const float4 LB4 = *(const float4*)&LB[jb];
                        uint2 old = *(const uint2*)&g16[q * BP + jb];
                        float nv[4];
                        nv[0] = bf2f((unsigned short)(old.x & 0xffffu))  + (val[t][0] - mu) * rstd * LG4.x + LB4.x;
                        nv[1] = bf2f((unsigned short)(old.x >> 16))      + (val[t][1] - mu) * rstd * LG4.y + LB4.y;
                        nv[2] = bf2f((unsigned short)(old.y & 0xffffu))  + (val[t][2] - mu) * rstd * LG4.z + LB4.z;
                        nv[3] = bf2f((unsigned short)(old.y >> 16))      + (val[t][3] - mu) * rstd * LG4.w + LB4.w;
                        uint2 nw;
                        nw.x = cvtpk(nv[0], nv[1]);
                        nw.y = cvtpk(nv[2], nv[3]);
                        *(uint2*)&g16[q * BP + jb] = nw;
                    }
                }
            }
            if (tid < 128) qss_s[tid] = 0.0f;   // reset for next layer's A1
        }
        __syncthreads();  // B6: end of layer
    }

    // ---------------- Final: gr = env^T g / NNEI ; d = gr^T gr[:, :16] -------
    for (int idx = tid; idx < 4 * MDIM; idx += 1024){
        const int c = idx / MDIM, mm = idx - c * MDIM;
        float a = 0.0f;
        for (int k = 0; k < NNEI; ++k)
            a = fmaf(env_s[k * 4 + c], bf2f(g16[k * BP + mm]), a);
        gr_s[c * MDIM + mm] = a * (1.0f / 120.0f);
    }
    __syncthreads();

    float* outp = out + (size_t)n * OUTD;
    for (int idx = tid; idx < MDIM * 16; idx += 1024){
        const int mm = idx >> 4, aa = idx & 15;
        float acc = 0.0f;
        #pragma unroll
        for (int c = 0; c < 4; ++c)
            acc = fmaf(gr_s[c * MDIM + mm], gr_s[c * MDIM + aa], acc);
        outp[idx] = acc;
    }
    if (tid < 8) outp[1600 + tid] = tebd_s[ta_sh * 8 + tid];
}

extern "C" void kernel_launch(void* const* d_in, const int* in_sizes, int n_in,
                              void* d_out, int out_size, void* d_ws, size_t ws_size,
                              hipStream_t stream) {
    const float* rij   = (const float*)d_in[0];
    const void*  nmask = d_in[1];
    const int*   atype = (const int*)d_in[2];
    const int*   ntype = (const int*)d_in[3];
    const float* tebd  = (const float*)d_in[4];
    const float* ew0 = (const float*)d_in[5];
    const float* eb0 = (const float*)d_in[6];
    const float* ew1 = (const float*)d_in[7];
    const float* eb1 = (const float*)d_in[8];
    const float* ew2 = (const float*)d_in[9];
    const float* eb2 = (const float*)d_in[10];
    const float* wq = (const float*)d_in[11];
    const float* bq = (const float*)d_in[12];
    const float* wk = (const float*)d_in[13];
    const float* bk = (const float*)d_in[14];
    const float* wv = (const float*)d_in[15];
    const float* bv = (const float*)d_in[16];
    const float* wo = (const float*)d_in[17];
    const float* bo = (const float*)d_in[18];
    const float* lng = (const float*)d_in[19];
    const float* lnb = (const float*)d_in[20];
    float* out = (float*)d_out;
    int* flag = (int*)d_ws;
    unsigned short* wsb = (unsigned short*)((char*)d_ws + 256);

    detect_mask_kernel<<<1, 64, 0, stream>>>((const unsigned char*)nmask, flag);
    prep_weights<<<276, 64, 0, stream>>>(wq, wk, wv, wo, ew2, ew0, ew1, wsb);
    dpa1_kernel<<<4096, 1024, 0, stream>>>(rij, nmask, atype, ntype, tebd,
                                           eb0, eb1, eb2,
                                           bq, bk, bv, bo, lng, lnb,
                                           out, flag, wsb);
}

// Round 16
// 722.873 us; speedup vs baseline: 1.1173x; 1.1173x over previous
//
#include <hip/hip_runtime.h>

// DescrptDPA1 on gfx950 — R16: R14 + consumer-side norm folds (raw K/V stored
// immediately in A1, scales published via kss_s/vss_s, applied in Core1) —
// deletes kv/vv live arrays WITHOUT recompute (R15's mistake).
// NF=1, NLOC=4096, NNEI=120, TEBD=8, NTYPES=4, M=100, ATTN=128, NLAYER=2, AXIS=16.

#define NNEI 120
#define MDIM 100
#define ADIM 128
#define BP   136   // bf16 pitch (272B rows; 68 dw = 4 mod 32 banks, 16B aligned)
#define H2P  72    // bf16 pitch for h2 staging
#define XP   40    // bf16 pitch for x / h1 staging (80B rows, 16B aligned)
#define OUTD 1608

typedef __attribute__((ext_vector_type(8))) short bf16x8;
typedef __attribute__((ext_vector_type(4))) float f32x4;

__device__ __forceinline__ float bf2f(unsigned short u){
    return __uint_as_float(((unsigned int)u) << 16);
}
__device__ __forceinline__ unsigned short f2bf(float f){
    unsigned int x = __float_as_uint(f);
    return (unsigned short)((x + 0x7fffu + ((x >> 16) & 1u)) >> 16);
}
__device__ __forceinline__ unsigned int cvtpk(float lo, float hi){
    unsigned int r;
    asm("v_cvt_pk_bf16_f32 %0, %1, %2" : "=v"(r) : "v"(lo), "v"(hi));
    return r;
}
__device__ __forceinline__ float ftanh(float x){
    return 1.0f - 2.0f / (__expf(2.0f * x) + 1.0f);
}
__device__ __forceinline__ float red16(float v){
    v += __shfl_xor(v, 1, 64); v += __shfl_xor(v, 2, 64);
    v += __shfl_xor(v, 4, 64); v += __shfl_xor(v, 8, 64);
    return v;
}

// nmask storage detection: 1 = int32 {0,1}, 2 = f32 {0.0,1.0}, 0 = byte bool
__global__ void detect_mask_kernel(const unsigned char* __restrict__ p,
                                   int* __restrict__ flag){
    if (blockIdx.x == 0 && threadIdx.x == 0){
        const unsigned int* u = (const unsigned int*)p;
        int alli = 1, allf = 1;
        for (int i = 0; i < 64; ++i){
            unsigned int w = u[i];
            if (!(w == 0u || w == 1u)) alli = 0;
            if (!(w == 0u || w == 0x3f800000u)) allf = 0;
        }
        flag[0] = alli ? 1 : (allf ? 2 : 0);
    }
}

// Pack weights (bf16). Frag = [64 lanes][8 bf16] = 1024B.
// QKV B-frags: fid = ((l*3+mat)*8+nt)*4+ks            (0..191)
// WO A-frags:  fid = 192 + (l*8+jt)*4+ks              (192..255, jt=7 zero)
// ew2 B-frags: fid = 256 + nt*2 + ks                  (256..269)
// ew0 B-frags: fid = 270 + nt   (nt=0,1; K=17 pad 32) (270..271)
// ew1 B-frags: fid = 272 + nt   (nt=0..3; K=25 pad 32)(272..275)
__global__ void prep_weights(const float* __restrict__ wq, const float* __restrict__ wk,
                             const float* __restrict__ wv, const float* __restrict__ wo,
                             const float* __restrict__ ew2, const float* __restrict__ ew0,
                             const float* __restrict__ ew1,
                             unsigned short* __restrict__ wsb){
    const int fid = blockIdx.x;
    const int lane = threadIdx.x;  // 64
    unsigned short* dst = wsb + (size_t)fid * 512 + lane * 8;
    if (fid < 192){
        const int l = fid / 96, rem = fid % 96, mat = rem / 32;
        const int r2 = rem % 32, nt = r2 / 4, ks = r2 % 4;
        const float* W = (mat == 0 ? wq : mat == 1 ? wk : wv) + l * MDIM * ADIM;
        const int nn = nt * 16 + (lane & 15);
        const int k0 = ks * 32 + (lane >> 4) * 8;
        #pragma unroll
        for (int i = 0; i < 8; ++i){
            const int kk = k0 + i;
            dst[i] = (kk < MDIM) ? f2bf(W[kk * ADIM + nn]) : (unsigned short)0;
        }
    } else if (fid < 256){
        const int f2 = fid - 192, l = f2 / 32, rem = f2 % 32, jt = rem / 4, ks = rem % 4;
        const float* W = wo + l * ADIM * MDIM;
        const int j = jt * 16 + (lane & 15);
        const int d0 = ks * 32 + (lane >> 4) * 8;
        #pragma unroll
        for (int i = 0; i < 8; ++i)
            dst[i] = (j < MDIM) ? f2bf(W[(d0 + i) * MDIM + j]) : (unsigned short)0;
    } else if (fid < 270){
        const int f3 = fid - 256, nt = f3 >> 1, ks = f3 & 1;
        const int nn = nt * 16 + (lane & 15);
        const int k0 = ks * 32 + (lane >> 4) * 8;
        #pragma unroll
        for (int i = 0; i < 8; ++i){
            const int kk = k0 + i;
            dst[i] = (kk < 50 && nn < MDIM) ? f2bf(ew2[kk * MDIM + nn]) : (unsigned short)0;
        }
    } else if (fid < 272){
        const int nt = fid - 270;
        const int nn = nt * 16 + (lane & 15);
        const int k0 = (lane >> 4) * 8;
        #pragma unroll
        for (int i = 0; i < 8; ++i){
            const int kk = k0 + i;
            dst[i] = (kk < 17 && nn < 25) ? f2bf(ew0[kk * 25 + nn]) : (unsigned short)0;
        }
    } else {
        const int nt = fid - 272;
        const int nn = nt * 16 + (lane & 15);
        const int k0 = (lane >> 4) * 8;
        #pragma unroll
        for (int i = 0; i < 8; ++i){
            const int kk = k0 + i;
            dst[i] = (kk < 25 && nn < 50) ? f2bf(ew1[kk * 50 + nn]) : (unsigned short)0;
        }
    }
}

__global__ __launch_bounds__(1024) void dpa1_kernel(
    const float* __restrict__ rij, const void* __restrict__ nmask,
    const int* __restrict__ atype, const int* __restrict__ ntype,
    const float* __restrict__ tebd,
    const float* __restrict__ eb0, const float* __restrict__ eb1,
    const float* __restrict__ eb2,
    const float* __restrict__ bq, const float* __restrict__ bk,
    const float* __restrict__ bv, const float* __restrict__ bo,
    const float* __restrict__ lng, const float* __restrict__ lnb,
    float* __restrict__ out, const int* __restrict__ flagp,
    const unsigned short* __restrict__ wsb)
{
    __shared__ __align__(16) unsigned short g16[128 * BP];   // bf16 g master
    __shared__ __align__(16) unsigned short buf1[128 * BP];  // h2 -> Qraw -> P~
    __shared__ __align__(16) unsigned short kn_s[128 * BP];  // x -> Kraw -> O'
    __shared__ __align__(16) unsigned short vT_s[128 * BP];  // h1 -> Vraw^T
    __shared__ float psum_s[256];
    __shared__ float lnp_s[512];
    __shared__ float qss_s[128];          // |Q row|^2 accumulators
    __shared__ __align__(16) float kss_s[128];  // tinv * rsqrt(|K row|^2)
    __shared__ __align__(16) float vss_s[128];  // swm_k * rsqrt(|V row|^2)
    __shared__ __align__(16) float env_s[128 * 4];
    __shared__ __align__(16) float rhat_s[128 * 4];
    __shared__ __align__(16) float swm_s[128];
    __shared__ __align__(16) float msk_s[128];
    __shared__ float tebd_s[32];
    __shared__ float gr_s[4 * MDIM];
    __shared__ int ta_sh;

    const int n    = blockIdx.x;
    const int tid  = threadIdx.x;
    const int lane = tid & 63;
    const int wid  = tid >> 6;
    const int flag = flagp[0];
    const int l15  = lane & 15;
    const int lg4  = lane >> 4;

    if (tid < 32) tebd_s[tid] = tebd[tid];
    if (tid == 0) ta_sh = atype[n];

    // ---------------- P-geom: geometry + x staging + zero g16 ----------------
    {
        unsigned int* z0 = (unsigned int*)g16;
        for (int i = tid; i < 128 * (BP/2); i += 1024) z0[i] = 0;
    }
    if (tid < 128){
        const int k = tid;
        unsigned short xr[2 * XP];
        #pragma unroll
        for (int i = 0; i < 2 * XP; ++i) xr[i] = 0;
        if (k < NNEI){
            const int base = n * NNEI + k;
            const float rx = rij[base * 3 + 0];
            const float ry = rij[base * 3 + 1];
            const float rz = rij[base * 3 + 2];
            const float r  = sqrtf(rx * rx + ry * ry + rz * rz);
            float mval;
            if (flag == 1)      mval = (((const int*)nmask)[base] != 0) ? 1.0f : 0.0f;
            else if (flag == 2) mval = ((const float*)nmask)[base];
            else                mval = (((const unsigned char*)nmask)[base] != 0) ? 1.0f : 0.0f;
            float uu = (r - 0.5f) * (1.0f / 5.5f);
            uu = fminf(fmaxf(uu, 0.0f), 1.0f);
            const float sw   = uu * uu * uu * (-6.0f * uu * uu + 15.0f * uu - 10.0f) + 1.0f;
            const float invr = 1.0f / r;
            const float sr   = sw * invr * mval;
            const float hx = rx * invr, hy = ry * invr, hz = rz * invr;
            env_s[k * 4 + 0] = sr;
            env_s[k * 4 + 1] = sr * hx;
            env_s[k * 4 + 2] = sr * hy;
            env_s[k * 4 + 3] = sr * hz;
            rhat_s[k * 4 + 0] = hx; rhat_s[k * 4 + 1] = hy; rhat_s[k * 4 + 2] = hz;
            rhat_s[k * 4 + 3] = 0.0f;
            swm_s[k] = sw * mval;
            msk_s[k] = mval;
            const int tn = ntype[base] * 8;
            const int tc = atype[n] * 8;
            xr[0] = f2bf(sr);
            #pragma unroll
            for (int i = 0; i < 8; ++i){
                xr[1 + i] = f2bf(tebd[tn + i]);
                xr[9 + i] = f2bf(tebd[tc + i]);
            }
        } else {
            env_s[k*4+0] = env_s[k*4+1] = env_s[k*4+2] = env_s[k*4+3] = 0.0f;
            rhat_s[k*4+0] = rhat_s[k*4+1] = rhat_s[k*4+2] = rhat_s[k*4+3] = 0.0f;
            swm_s[k] = 0.0f; msk_s[k] = 0.0f;
        }
        #pragma unroll
        for (int c = 0; c < 5; ++c)
            *(uint4*)&kn_s[k * XP + c * 8] = *(const uint4*)&xr[c * 8];
    }
    __syncthreads();

    // ---------------- e1 (MFMA): h1 = tanh(x @ ew0 + eb0) -> vT_s bf16 -------
    {
        const int mt = wid >> 1, nt = wid & 1;   // 16 jobs, 1 per wave
        bf16x8 a = *(const bf16x8*)&kn_s[(mt*16 + l15) * XP + lg4 * 8];
        bf16x8 b = *(const bf16x8*)(wsb + (size_t)(270 + nt) * 512 + lane * 8);
        f32x4 C = (f32x4){0.f, 0.f, 0.f, 0.f};
        C = __builtin_amdgcn_mfma_f32_16x16x32_bf16(a, b, C, 0, 0, 0);
        const int j = nt * 16 + l15;
        const float ebj = (j < 25) ? eb0[j] : 0.0f;
        #pragma unroll
        for (int r = 0; r < 4; ++r){
            const int row = mt * 16 + lg4 * 4 + r;
            const float v = (row < NNEI && j < 25) ? ftanh(C[r] + ebj) : 0.0f;
            vT_s[row * XP + j] = f2bf(v);
        }
    }
    __syncthreads();

    // ---------------- e2 (MFMA): h2 = tanh(h1 @ ew1 + eb1) + [h1,h1] -> buf1 --
    {
        for (int jb = wid; jb < 32; jb += 16){   // 2 jobs per wave
            const int mt = jb >> 2, nt = jb & 3;
            bf16x8 a = *(const bf16x8*)&vT_s[(mt*16 + l15) * XP + lg4 * 8];
            bf16x8 b = *(const bf16x8*)(wsb + (size_t)(272 + nt) * 512 + lane * 8);
            f32x4 C = (f32x4){0.f, 0.f, 0.f, 0.f};
            C = __builtin_amdgcn_mfma_f32_16x16x32_bf16(a, b, C, 0, 0, 0);
            const int j2 = nt * 16 + l15;
            const float ebj = (j2 < 50) ? eb1[j2] : 0.0f;
            const int jr = (j2 >= 25) ? j2 - 25 : j2;
            #pragma unroll
            for (int r = 0; r < 4; ++r){
                const int row = mt * 16 + lg4 * 4 + r;
                float v = 0.0f;
                if (row < NNEI && j2 < 50){
                    const float h1d = bf2f(vT_s[row * XP + jr]);
                    v = ftanh(C[r] + ebj) + h1d;
                }
                buf1[row * H2P + j2] = f2bf(v);
            }
        }
    }
    __syncthreads();

    // ---------------- e3: g = (tanh(h2 @ ew2 + eb2) + [h2,h2]) * m  (MFMA) ---
    {
        for (int job = wid; job < 56; job += 16){
            const int mt = job / 7, nt = job - mt * 7;
            bf16x8 a0 = *(const bf16x8*)&buf1[(mt*16 + l15) * H2P + 0*32 + lg4 * 8];
            bf16x8 a1 = *(const bf16x8*)&buf1[(mt*16 + l15) * H2P + 1*32 + lg4 * 8];
            bf16x8 b0 = *(const bf16x8*)(wsb + (size_t)(256 + nt*2 + 0) * 512 + lane * 8);
            bf16x8 b1 = *(const bf16x8*)(wsb + (size_t)(256 + nt*2 + 1) * 512 + lane * 8);
            f32x4 C = (f32x4){0.f, 0.f, 0.f, 0.f};
            C = __builtin_amdgcn_mfma_f32_16x16x32_bf16(a0, b0, C, 0, 0, 0);
            C = __builtin_amdgcn_mfma_f32_16x16x32_bf16(a1, b1, C, 0, 0, 0);
            const int j = nt * 16 + l15;
            if (j < MDIM){
                const float ebj = eb2[j];
                const int jr = (j >= 50) ? j - 50 : j;
                #pragma unroll
                for (int r = 0; r < 4; ++r){
                    const int row = mt * 16 + lg4 * 4 + r;
                    if (row < NNEI){
                        const float h2d = bf2f(buf1[row * H2P + jr]);
                        const float t = ftanh(C[r] + ebj) + h2d;
                        g16[row * BP + j] = f2bf(t * msk_s[row]);
                    }
                }
            }
        }
        if (tid < 128) qss_s[tid] = 0.0f;
    }
    __syncthreads();

    // ---------------- Attention layers ----------------
    const float tinv = 0.08838834764831845f;  // 1/sqrt(128)
    const int qt = wid >> 1;   // core pair: q-tile
    const int hh = wid & 1;    // core pair: half index
    const int q  = qt * 16 + l15;

    for (int l = 0; l < 2; ++l){
        // ===== A1 (balanced, raw store): each wave = 1 full K-or-V job
        //       (store raw, publish scale) + 1 half raw-Q job (same tile) ====
        {
            const int t = wid & 7;
            bf16x8 ag[4];
            #pragma unroll
            for (int ks = 0; ks < 4; ++ks)
                ag[ks] = *(const bf16x8*)&g16[(t*16 + l15) * BP + ks*32 + lg4 * 8];
            if (wid < 8){
                // K tile t: store raw K; publish kss = tinv*rsqrt(rowsum)
                float sq[4] = {0.f, 0.f, 0.f, 0.f};
                #pragma unroll
                for (int nt = 0; nt < 8; ++nt){
                    f32x4 C = (f32x4){0.f, 0.f, 0.f, 0.f};
                    #pragma unroll
                    for (int ks = 0; ks < 4; ++ks){
                        bf16x8 b = *(const bf16x8*)(wsb + (size_t)(((l*3+1)*8+nt)*4+ks) * 512 + lane * 8);
                        C = __builtin_amdgcn_mfma_f32_16x16x32_bf16(ag[ks], b, C, 0, 0, 0);
                    }
                    const float bias = bk[l * ADIM + nt*16 + l15];
                    #pragma unroll
                    for (int r = 0; r < 4; ++r){
                        const float v = C[r] + bias;
                        kn_s[(t*16 + lg4*4 + r) * BP + nt*16 + l15] = f2bf(v);
                        sq[r] = fmaf(v, v, sq[r]);
                    }
                }
                #pragma unroll
                for (int r = 0; r < 4; ++r){
                    const float s = red16(sq[r]);
                    if (l15 == 0) kss_s[t*16 + lg4*4 + r] = tinv * rsqrtf(fmaxf(s, 1e-24f));
                }
            } else {
                // V tile t: store raw V^T; publish vss = swm_k*rsqrt(rowsum)
                float sq[4] = {0.f, 0.f, 0.f, 0.f};
                #pragma unroll
                for (int nt = 0; nt < 8; ++nt){
                    f32x4 C = (f32x4){0.f, 0.f, 0.f, 0.f};
                    #pragma unroll
                    for (int ks = 0; ks < 4; ++ks){
                        bf16x8 b = *(const bf16x8*)(wsb + (size_t)(((l*3+2)*8+nt)*4+ks) * 512 + lane * 8);
                        C = __builtin_amdgcn_mfma_f32_16x16x32_bf16(ag[ks], b, C, 0, 0, 0);
                    }
                    const float bias = bv[l * ADIM + nt*16 + l15];
                    float v0 = C[0] + bias, v1 = C[1] + bias;
                    float v2 = C[2] + bias, v3 = C[3] + bias;
                    sq[0] = fmaf(v0, v0, sq[0]); sq[1] = fmaf(v1, v1, sq[1]);
                    sq[2] = fmaf(v2, v2, sq[2]); sq[3] = fmaf(v3, v3, sq[3]);
                    *(uint2*)&vT_s[(nt*16 + l15) * BP + t*16 + lg4*4] =
                        make_uint2(cvtpk(v0, v1), cvtpk(v2, v3));
                }
                #pragma unroll
                for (int r = 0; r < 4; ++r){
                    const int k = t*16 + lg4*4 + r;
                    const float s = red16(sq[r]);
                    if (l15 == 0) vss_s[k] = swm_s[k] * rsqrtf(fmaxf(s, 1e-24f));
                }
            }
            __builtin_amdgcn_sched_barrier(0);
            // Half-width raw-Q job on the SAME tile t, half hq = wid>>3
            {
                const int hq = wid >> 3;
                float sq2[4] = {0.f, 0.f, 0.f, 0.f};
                #pragma unroll
                for (int u = 0; u < 4; ++u){
                    const int nt = hq*4 + u;
                    f32x4 C = (f32x4){0.f, 0.f, 0.f, 0.f};
                    #pragma unroll
                    for (int ks = 0; ks < 4; ++ks){
                        bf16x8 b = *(const bf16x8*)(wsb + (size_t)(((l*3+0)*8+nt)*4+ks) * 512 + lane * 8);
                        C = __builtin_amdgcn_mfma_f32_16x16x32_bf16(ag[ks], b, C, 0, 0, 0);
                    }
                    const float bias = bq[l * ADIM + nt*16 + l15];
                    #pragma unroll
                    for (int r = 0; r < 4; ++r){
                        const float v = C[r] + bias;
                        buf1[(t*16 + lg4*4 + r) * BP + nt*16 + l15] = f2bf(v);
                        sq2[r] = fmaf(v, v, sq2[r]);
                    }
                }
                #pragma unroll
                for (int r = 0; r < 4; ++r){
                    const float s = red16(sq2[r]);
                    if (l15 == 0) atomicAdd(&qss_s[t*16 + lg4*4 + r], s);
                }
            }
        }
        __syncthreads();  // B1: Qraw, Kraw, Vraw^T, qss/kss/vss ready

        // ===== Core1: scores half (wave pair qt,hh); consumer-side scales ====
        unsigned int pw0[4], pw1[4];
        float tot;
        {
            bf16x8 bqf[4];
            #pragma unroll
            for (int ks = 0; ks < 4; ++ks)
                bqf[ks] = *(const bf16x8*)&buf1[(qt*16 + l15) * BP + ks*32 + lg4 * 8];
            f32x4 Cs[4];
            #pragma unroll
            for (int t = 0; t < 4; ++t) Cs[t] = (f32x4){0.f, 0.f, 0.f, 0.f};
            #pragma unroll
            for (int t = 0; t < 4; ++t)
                #pragma unroll
                for (int ks = 0; ks < 4; ++ks){
                    bf16x8 a = *(const bf16x8*)&kn_s[((hh*4+t)*16 + l15) * BP + ks*32 + lg4 * 8];
                    Cs[t] = __builtin_amdgcn_mfma_f32_16x16x32_bf16(a, bqf[ks], Cs[t], 0, 0, 0);
                }
            const float qi = rsqrtf(fmaxf(qss_s[q], 1e-24f));
            const float4 rq = *(const float4*)&rhat_s[q * 4];
            tot = 0.f;
            #pragma unroll
            for (int t = 0; t < 4; ++t){
                const int kb = (hh*4+t)*16 + lg4*4;
                const float4 ks4 = *(const float4*)&kss_s[kb];
                const float4 vs4 = *(const float4*)&vss_s[kb];
                float p[4];
                #pragma unroll
                for (int r = 0; r < 4; ++r){
                    const float e = __expf(Cs[t][r] * qi * ((const float*)&ks4)[r]) * msk_s[kb + r];
                    tot += e;
                    const float4 rk = *(const float4*)&rhat_s[(kb + r) * 4];
                    p[r] = e * (rq.x*rk.x + rq.y*rk.y + rq.z*rk.z) * ((const float*)&vs4)[r];
                }
                pw0[t] = cvtpk(p[0], p[1]);
                pw1[t] = cvtpk(p[2], p[3]);
            }
            tot += __shfl_xor(tot, 16, 64);
            tot += __shfl_xor(tot, 32, 64);
        }
        __syncthreads();  // B2: all Q/K reads done; buf1/kn rows reusable

        // ===== Core2: publish P~ (= e*gate*vss) and psum =====
        #pragma unroll
        for (int t = 0; t < 4; ++t)
            *(uint2*)&buf1[(qt*16 + l15) * BP + (hh*4+t)*16 + lg4*4] = make_uint2(pw0[t], pw1[t]);
        if (lg4 == 0) psum_s[q * 2 + hh] = tot;
        __syncthreads();  // B3: P~, psum visible

        // ===== Core3: PV half; apply rsum to O'; publish O' =====
        {
            bf16x8 bpf[4];
            #pragma unroll
            for (int ks = 0; ks < 4; ++ks)
                bpf[ks] = *(const bf16x8*)&buf1[(qt*16 + l15) * BP + ks*32 + lg4 * 8];
            f32x4 Co[4];
            #pragma unroll
            for (int t = 0; t < 4; ++t) Co[t] = (f32x4){0.f, 0.f, 0.f, 0.f};
            #pragma unroll
            for (int t = 0; t < 4; ++t)
                #pragma unroll
                for (int ks = 0; ks < 4; ++ks){
                    bf16x8 a = *(const bf16x8*)&vT_s[((hh*4+t)*16 + l15) * BP + ks*32 + lg4 * 8];
                    Co[t] = __builtin_amdgcn_mfma_f32_16x16x32_bf16(a, bpf[ks], Co[t], 0, 0, 0);
                }
            const float totq = psum_s[q * 2] + psum_s[q * 2 + 1];
            const float rsum = (totq > 0.0f) ? swm_s[q] / totq : 0.0f;
            #pragma unroll
            for (int t = 0; t < 4; ++t){
                const unsigned int lo = cvtpk(Co[t][0] * rsum, Co[t][1] * rsum);
                const unsigned int hi = cvtpk(Co[t][2] * rsum, Co[t][3] * rsum);
                *(uint2*)&kn_s[(qt*16 + l15) * BP + (hh*4+t)*16 + lg4*4] = make_uint2(lo, hi);
            }
        }
        __syncthreads();  // B4: O' visible

        // ===== Core4: out-proj half + LN partials =====
        float val[4][4];
        {
            bf16x8 bof[4];
            #pragma unroll
            for (int ks = 0; ks < 4; ++ks)
                bof[ks] = *(const bf16x8*)&kn_s[(qt*16 + l15) * BP + ks*32 + lg4 * 8];
            const float* BO = bo + l * MDIM;
            float sv = 0.f, sv2 = 0.f;
            #pragma unroll
            for (int t = 0; t < 4; ++t){
                const int jt = hh*4 + t;
                f32x4 Cf = (f32x4){0.f, 0.f, 0.f, 0.f};
                #pragma unroll
                for (int ks = 0; ks < 4; ++ks){
                    bf16x8 a = *(const bf16x8*)(wsb + (size_t)(192 + (l*8+jt)*4 + ks) * 512 + lane * 8);
                    Cf = __builtin_amdgcn_mfma_f32_16x16x32_bf16(a, bof[ks], Cf, 0, 0, 0);
                }
                const bool jok = (jt < 6) || (jt == 6 && lg4 == 0);
                float4 BO4 = jok ? *(const float4*)&BO[jt*16 + lg4*4] : make_float4(0,0,0,0);
                #pragma unroll
                for (int r = 0; r < 4; ++r){
                    const float v = Cf[r] + ((const float*)&BO4)[r];
                    val[t][r] = v;
                    if (jok){ sv += v; sv2 += v * v; }
                }
            }
            sv  += __shfl_xor(sv, 16, 64);  sv  += __shfl_xor(sv, 32, 64);
            sv2 += __shfl_xor(sv2, 16, 64); sv2 += __shfl_xor(sv2, 32, 64);
            if (lg4 == 0){
                lnp_s[q * 4 + hh * 2 + 0] = sv;
                lnp_s[q * 4 + hh * 2 + 1] = sv2;
            }
        }
        __syncthreads();  // B5: LN partials visible

        // ===== Core5: LayerNorm apply + residual into g16 (own jt half) =====
        {
            const float* LG = lng + l * MDIM;
            const float* LB = lnb + l * MDIM;
            const float svt  = lnp_s[q * 4 + 0] + lnp_s[q * 4 + 2];
            const float sv2t = lnp_s[q * 4 + 1] + lnp_s[q * 4 + 3];
            const float mu   = svt * 0.01f;
            const float var  = sv2t * 0.01f - mu * mu;
            const float rstd = rsqrtf(var + 1e-5f);
            if (q < NNEI){
                #pragma unroll
                for (int t = 0; t < 4; ++t){
                    const int jt = hh*4 + t;
                    const bool jok = (jt < 6) || (jt == 6 && lg4 == 0);
                    if (jok){
                        const int jb = jt*16 + lg4*4;
                        const float4 LG4 = *(const float4*)&LG[jb];
                        const float4 LB4 = *(const float4*)&LB[jb];
                        uint2 old = *(const uint2*)&g16[q * BP + jb];
                        float nv[4];
                        nv[0] = bf2f((unsigned short)(old.x & 0xffffu))  + (val[t][0] - mu) * rstd * LG4.x + LB4.x;
                        nv[1] = bf2f((unsigned short)(old.x >> 16))      + (val[t][1] - mu) * rstd * LG4.y + LB4.y;
                        nv[2] = bf2f((unsigned short)(old.y & 0xffffu))  + (val[t][2] - mu) * rstd * LG4.z + LB4.z;
                        nv[3] = bf2f((unsigned short)(old.y >> 16))      + (val[t][3] - mu) * rstd * LG4.w + LB4.w;
                        uint2 nw;
                        nw.x = cvtpk(nv[0], nv[1]);
                        nw.y = cvtpk(nv[2], nv[3]);
                        *(uint2*)&g16[q * BP + jb] = nw;
                    }
                }
            }
            if (tid < 128) qss_s[tid] = 0.0f;   // reset for next layer's A1
        }
        __syncthreads();  // B6: end of layer
    }

    // ---------------- Final: gr = env^T g / NNEI ; d = gr^T gr[:, :16] -------
    for (int idx = tid; idx < 4 * MDIM; idx += 1024){
        const int c = idx / MDIM, mm = idx - c * MDIM;
        float a = 0.0f;
        for (int k = 0; k < NNEI; ++k)
            a = fmaf(env_s[k * 4 + c], bf2f(g16[k * BP + mm]), a);
        gr_s[c * MDIM + mm] = a * (1.0f / 120.0f);
    }
    __syncthreads();

    float* outp = out + (size_t)n * OUTD;
    for (int idx = tid; idx < MDIM * 16; idx += 1024){
        const int mm = idx >> 4, aa = idx & 15;
        float acc = 0.0f;
        #pragma unroll
        for (int c = 0; c < 4; ++c)
            acc = fmaf(gr_s[c * MDIM + mm], gr_s[c * MDIM + aa], acc);
        outp[idx] = acc;
    }
    if (tid < 8) outp[1600 + tid] = tebd_s[ta_sh * 8 + tid];
}

extern "C" void kernel_launch(void* const* d_in, const int* in_sizes, int n_in,
                              void* d_out, int out_size, void* d_ws, size_t ws_size,
                              hipStream_t stream) {
    const float* rij   = (const float*)d_in[0];
    const void*  nmask = d_in[1];
    const int*   atype = (const int*)d_in[2];
    const int*   ntype = (const int*)d_in[3];
    const float* tebd  = (const float*)d_in[4];
    const float* ew0 = (const float*)d_in[5];
    const float* eb0 = (const float*)d_in[6];
    const float* ew1 = (const float*)d_in[7];
    const float* eb1 = (const float*)d_in[8];
    const float* ew2 = (const float*)d_in[9];
    const float* eb2 = (const float*)d_in[10];
    const float* wq = (const float*)d_in[11];
    const float* bq = (const float*)d_in[12];
    const float* wk = (const float*)d_in[13];
    const float* bk = (const float*)d_in[14];
    const float* wv = (const float*)d_in[15];
    const float* bv = (const float*)d_in[16];
    const float* wo = (const float*)d_in[17];
    const float* bo = (const float*)d_in[18];
    const float* lng = (const float*)d_in[19];
    const float* lnb = (const float*)d_in[20];
    float* out = (float*)d_out;
    int* flag = (int*)d_ws;
    unsigned short* wsb = (unsigned short*)((char*)d_ws + 256);

    detect_mask_kernel<<<1, 64, 0, stream>>>((const unsigned char*)nmask, flag);
    prep_weights<<<276, 64, 0, stream>>>(wq, wk, wv, wo, ew2, ew0, ew1, wsb);
    dpa1_kernel<<<4096, 1024, 0, stream>>>(rij, nmask, atype, ntype, tebd,
                                           eb0, eb1, eb2,
                                           bq, bk, bv, bo, lng, lnb,
                                           out, flag, wsb);
}

// Round 17
// 703.289 us; speedup vs baseline: 1.1484x; 1.0278x over previous
//
#include <hip/hip_runtime.h>

// DescrptDPA1 on gfx950 — R17: R16 + gate via MFMA (G = rhatK·rhatQ^T from
// bf16-staged rh16[128][40]; replaces 48 VALU FMA + 16 LDS float4 reads per
// thread per layer with 4 MFMA + 5 b128 reads).
// NF=1, NLOC=4096, NNEI=120, TEBD=8, NTYPES=4, M=100, ATTN=128, NLAYER=2, AXIS=16.

#define NNEI 120
#define MDIM 100
#define ADIM 128
#define BP   136   // bf16 pitch (272B rows; 68 dw = 4 mod 32 banks, 16B aligned)
#define H2P  72    // bf16 pitch for h2 staging
#define XP   40    // bf16 pitch for x / h1 staging (80B rows, 16B aligned)
#define RHP  40    // bf16 pitch for rhat staging (80B rows; 20 dw stride -> 2-way)
#define OUTD 1608

typedef __attribute__((ext_vector_type(8))) short bf16x8;
typedef __attribute__((ext_vector_type(4))) float f32x4;

__device__ __forceinline__ float bf2f(unsigned short u){
    return __uint_as_float(((unsigned int)u) << 16);
}
__device__ __forceinline__ unsigned short f2bf(float f){
    unsigned int x = __float_as_uint(f);
    return (unsigned short)((x + 0x7fffu + ((x >> 16) & 1u)) >> 16);
}
__device__ __forceinline__ unsigned int cvtpk(float lo, float hi){
    unsigned int r;
    asm("v_cvt_pk_bf16_f32 %0, %1, %2" : "=v"(r) : "v"(lo), "v"(hi));
    return r;
}
__device__ __forceinline__ float ftanh(float x){
    return 1.0f - 2.0f / (__expf(2.0f * x) + 1.0f);
}
__device__ __forceinline__ float red16(float v){
    v += __shfl_xor(v, 1, 64); v += __shfl_xor(v, 2, 64);
    v += __shfl_xor(v, 4, 64); v += __shfl_xor(v, 8, 64);
    return v;
}

// nmask storage detection: 1 = int32 {0,1}, 2 = f32 {0.0,1.0}, 0 = byte bool
__global__ void detect_mask_kernel(const unsigned char* __restrict__ p,
                                   int* __restrict__ flag){
    if (blockIdx.x == 0 && threadIdx.x == 0){
        const unsigned int* u = (const unsigned int*)p;
        int alli = 1, allf = 1;
        for (int i = 0; i < 64; ++i){
            unsigned int w = u[i];
            if (!(w == 0u || w == 1u)) alli = 0;
            if (!(w == 0u || w == 0x3f800000u)) allf = 0;
        }
        flag[0] = alli ? 1 : (allf ? 2 : 0);
    }
}

// Pack weights (bf16). Frag = [64 lanes][8 bf16] = 1024B.
// QKV B-frags: fid = ((l*3+mat)*8+nt)*4+ks            (0..191)
// WO A-frags:  fid = 192 + (l*8+jt)*4+ks              (192..255, jt=7 zero)
// ew2 B-frags: fid = 256 + nt*2 + ks                  (256..269)
// ew0 B-frags: fid = 270 + nt   (nt=0,1; K=17 pad 32) (270..271)
// ew1 B-frags: fid = 272 + nt   (nt=0..3; K=25 pad 32)(272..275)
__global__ void prep_weights(const float* __restrict__ wq, const float* __restrict__ wk,
                             const float* __restrict__ wv, const float* __restrict__ wo,
                             const float* __restrict__ ew2, const float* __restrict__ ew0,
                             const float* __restrict__ ew1,
                             unsigned short* __restrict__ wsb){
    const int fid = blockIdx.x;
    const int lane = threadIdx.x;  // 64
    unsigned short* dst = wsb + (size_t)fid * 512 + lane * 8;
    if (fid < 192){
        const int l = fid / 96, rem = fid % 96, mat = rem / 32;
        const int r2 = rem % 32, nt = r2 / 4, ks = r2 % 4;
        const float* W = (mat == 0 ? wq : mat == 1 ? wk : wv) + l * MDIM * ADIM;
        const int nn = nt * 16 + (lane & 15);
        const int k0 = ks * 32 + (lane >> 4) * 8;
        #pragma unroll
        for (int i = 0; i < 8; ++i){
            const int kk = k0 + i;
            dst[i] = (kk < MDIM) ? f2bf(W[kk * ADIM + nn]) : (unsigned short)0;
        }
    } else if (fid < 256){
        const int f2 = fid - 192, l = f2 / 32, rem = f2 % 32, jt = rem / 4, ks = rem % 4;
        const float* W = wo + l * ADIM * MDIM;
        const int j = jt * 16 + (lane & 15);
        const int d0 = ks * 32 + (lane >> 4) * 8;
        #pragma unroll
        for (int i = 0; i < 8; ++i)
            dst[i] = (j < MDIM) ? f2bf(W[(d0 + i) * MDIM + j]) : (unsigned short)0;
    } else if (fid < 270){
        const int f3 = fid - 256, nt = f3 >> 1, ks = f3 & 1;
        const int nn = nt * 16 + (lane & 15);
        const int k0 = ks * 32 + (lane >> 4) * 8;
        #pragma unroll
        for (int i = 0; i < 8; ++i){
            const int kk = k0 + i;
            dst[i] = (kk < 50 && nn < MDIM) ? f2bf(ew2[kk * MDIM + nn]) : (unsigned short)0;
        }
    } else if (fid < 272){
        const int nt = fid - 270;
        const int nn = nt * 16 + (lane & 15);
        const int k0 = (lane >> 4) * 8;
        #pragma unroll
        for (int i = 0; i < 8; ++i){
            const int kk = k0 + i;
            dst[i] = (kk < 17 && nn < 25) ? f2bf(ew0[kk * 25 + nn]) : (unsigned short)0;
        }
    } else {
        const int nt = fid - 272;
        const int nn = nt * 16 + (lane & 15);
        const int k0 = (lane >> 4) * 8;
        #pragma unroll
        for (int i = 0; i < 8; ++i){
            const int kk = k0 + i;
            dst[i] = (kk < 25 && nn < 50) ? f2bf(ew1[kk * 50 + nn]) : (unsigned short)0;
        }
    }
}

__global__ __launch_bounds__(1024) void dpa1_kernel(
    const float* __restrict__ rij, const void* __restrict__ nmask,
    const int* __restrict__ atype, const int* __restrict__ ntype,
    const float* __restrict__ tebd,
    const float* __restrict__ eb0, const float* __restrict__ eb1,
    const float* __restrict__ eb2,
    const float* __restrict__ bq, const float* __restrict__ bk,
    const float* __restrict__ bv, const float* __restrict__ bo,
    const float* __restrict__ lng, const float* __restrict__ lnb,
    float* __restrict__ out, const int* __restrict__ flagp,
    const unsigned short* __restrict__ wsb)
{
    __shared__ __align__(16) unsigned short g16[128 * BP];   // bf16 g master
    __shared__ __align__(16) unsigned short buf1[128 * BP];  // h2 -> Qraw -> P~
    __shared__ __align__(16) unsigned short kn_s[128 * BP];  // x -> Kraw -> O'
    __shared__ __align__(16) unsigned short vT_s[128 * BP];  // h1 -> Vraw^T
    __shared__ __align__(16) unsigned short rh16[128 * RHP]; // bf16 rhat (K=32 zero-pad)
    __shared__ float psum_s[256];
    __shared__ float lnp_s[512];
    __shared__ float qss_s[128];          // |Q row|^2 accumulators
    __shared__ __align__(16) float kss_s[128];  // tinv * rsqrt(|K row|^2)
    __shared__ __align__(16) float vss_s[128];  // swm_k * rsqrt(|V row|^2)
    __shared__ __align__(16) float env_s[128 * 4];
    __shared__ __align__(16) float rhat_s[128 * 4];
    __shared__ __align__(16) float swm_s[128];
    __shared__ __align__(16) float msk_s[128];
    __shared__ float tebd_s[32];
    __shared__ float gr_s[4 * MDIM];
    __shared__ int ta_sh;

    const int n    = blockIdx.x;
    const int tid  = threadIdx.x;
    const int lane = tid & 63;
    const int wid  = tid >> 6;
    const int flag = flagp[0];
    const int l15  = lane & 15;
    const int lg4  = lane >> 4;

    if (tid < 32) tebd_s[tid] = tebd[tid];
    if (tid == 0) ta_sh = atype[n];

    // ---------------- P-geom: geometry + x/rhat staging + zero g16 -----------
    {
        unsigned int* z0 = (unsigned int*)g16;
        for (int i = tid; i < 128 * (BP/2); i += 1024) z0[i] = 0;
    }
    if (tid < 128){
        const int k = tid;
        unsigned short xr[2 * XP];
        #pragma unroll
        for (int i = 0; i < 2 * XP; ++i) xr[i] = 0;
        unsigned short rr[32];
        #pragma unroll
        for (int i = 0; i < 32; ++i) rr[i] = 0;
        if (k < NNEI){
            const int base = n * NNEI + k;
            const float rx = rij[base * 3 + 0];
            const float ry = rij[base * 3 + 1];
            const float rz = rij[base * 3 + 2];
            const float r  = sqrtf(rx * rx + ry * ry + rz * rz);
            float mval;
            if (flag == 1)      mval = (((const int*)nmask)[base] != 0) ? 1.0f : 0.0f;
            else if (flag == 2) mval = ((const float*)nmask)[base];
            else                mval = (((const unsigned char*)nmask)[base] != 0) ? 1.0f : 0.0f;
            float uu = (r - 0.5f) * (1.0f / 5.5f);
            uu = fminf(fmaxf(uu, 0.0f), 1.0f);
            const float sw   = uu * uu * uu * (-6.0f * uu * uu + 15.0f * uu - 10.0f) + 1.0f;
            const float invr = 1.0f / r;
            const float sr   = sw * invr * mval;
            const float hx = rx * invr, hy = ry * invr, hz = rz * invr;
            env_s[k * 4 + 0] = sr;
            env_s[k * 4 + 1] = sr * hx;
            env_s[k * 4 + 2] = sr * hy;
            env_s[k * 4 + 3] = sr * hz;
            rhat_s[k * 4 + 0] = hx; rhat_s[k * 4 + 1] = hy; rhat_s[k * 4 + 2] = hz;
            rhat_s[k * 4 + 3] = 0.0f;
            swm_s[k] = sw * mval;
            msk_s[k] = mval;
            const int tn = ntype[base] * 8;
            const int tc = atype[n] * 8;
            xr[0] = f2bf(sr);
            #pragma unroll
            for (int i = 0; i < 8; ++i){
                xr[1 + i] = f2bf(tebd[tn + i]);
                xr[9 + i] = f2bf(tebd[tc + i]);
            }
            rr[0] = f2bf(hx); rr[1] = f2bf(hy); rr[2] = f2bf(hz);
        } else {
            env_s[k*4+0] = env_s[k*4+1] = env_s[k*4+2] = env_s[k*4+3] = 0.0f;
            rhat_s[k*4+0] = rhat_s[k*4+1] = rhat_s[k*4+2] = rhat_s[k*4+3] = 0.0f;
            swm_s[k] = 0.0f; msk_s[k] = 0.0f;
        }
        #pragma unroll
        for (int c = 0; c < 5; ++c)
            *(uint4*)&kn_s[k * XP + c * 8] = *(const uint4*)&xr[c * 8];
        #pragma unroll
        for (int c = 0; c < 4; ++c)
            *(uint4*)&rh16[k * RHP + c * 8] = *(const uint4*)&rr[c * 8];
    }
    __syncthreads();

    // ---------------- e1 (MFMA): h1 = tanh(x @ ew0 + eb0) -> vT_s bf16 -------
    {
        const int mt = wid >> 1, nt = wid & 1;   // 16 jobs, 1 per wave
        bf16x8 a = *(const bf16x8*)&kn_s[(mt*16 + l15) * XP + lg4 * 8];
        bf16x8 b = *(const bf16x8*)(wsb + (size_t)(270 + nt) * 512 + lane * 8);
        f32x4 C = (f32x4){0.f, 0.f, 0.f, 0.f};
        C = __builtin_amdgcn_mfma_f32_16x16x32_bf16(a, b, C, 0, 0, 0);
        const int j = nt * 16 + l15;
        const float ebj = (j < 25) ? eb0[j] : 0.0f;
        #pragma unroll
        for (int r = 0; r < 4; ++r){
            const int row = mt * 16 + lg4 * 4 + r;
            const float v = (row < NNEI && j < 25) ? ftanh(C[r] + ebj) : 0.0f;
            vT_s[row * XP + j] = f2bf(v);
        }
    }
    __syncthreads();

    // ---------------- e2 (MFMA): h2 = tanh(h1 @ ew1 + eb1) + [h1,h1] -> buf1 --
    {
        for (int jb = wid; jb < 32; jb += 16){   // 2 jobs per wave
            const int mt = jb >> 2, nt = jb & 3;
            bf16x8 a = *(const bf16x8*)&vT_s[(mt*16 + l15) * XP + lg4 * 8];
            bf16x8 b = *(const bf16x8*)(wsb + (size_t)(272 + nt) * 512 + lane * 8);
            f32x4 C = (f32x4){0.f, 0.f, 0.f, 0.f};
            C = __builtin_amdgcn_mfma_f32_16x16x32_bf16(a, b, C, 0, 0, 0);
            const int j2 = nt * 16 + l15;
            const float ebj = (j2 < 50) ? eb1[j2] : 0.0f;
            const int jr = (j2 >= 25) ? j2 - 25 : j2;
            #pragma unroll
            for (int r = 0; r < 4; ++r){
                const int row = mt * 16 + lg4 * 4 + r;
                float v = 0.0f;
                if (row < NNEI && j2 < 50){
                    const float h1d = bf2f(vT_s[row * XP + jr]);
                    v = ftanh(C[r] + ebj) + h1d;
                }
                buf1[row * H2P + j2] = f2bf(v);
            }
        }
    }
    __syncthreads();

    // ---------------- e3: g = (tanh(h2 @ ew2 + eb2) + [h2,h2]) * m  (MFMA) ---
    {
        for (int job = wid; job < 56; job += 16){
            const int mt = job / 7, nt = job - mt * 7;
            bf16x8 a0 = *(const bf16x8*)&buf1[(mt*16 + l15) * H2P + 0*32 + lg4 * 8];
            bf16x8 a1 = *(const bf16x8*)&buf1[(mt*16 + l15) * H2P + 1*32 + lg4 * 8];
            bf16x8 b0 = *(const bf16x8*)(wsb + (size_t)(256 + nt*2 + 0) * 512 + lane * 8);
            bf16x8 b1 = *(const bf16x8*)(wsb + (size_t)(256 + nt*2 + 1) * 512 + lane * 8);
            f32x4 C = (f32x4){0.f, 0.f, 0.f, 0.f};
            C = __builtin_amdgcn_mfma_f32_16x16x32_bf16(a0, b0, C, 0, 0, 0);
            C = __builtin_amdgcn_mfma_f32_16x16x32_bf16(a1, b1, C, 0, 0, 0);
            const int j = nt * 16 + l15;
            if (j < MDIM){
                const float ebj = eb2[j];
                const int jr = (j >= 50) ? j - 50 : j;
                #pragma unroll
                for (int r = 0; r < 4; ++r){
                    const int row = mt * 16 + lg4 * 4 + r;
                    if (row < NNEI){
                        const float h2d = bf2f(buf1[row * H2P + jr]);
                        const float t = ftanh(C[r] + ebj) + h2d;
                        g16[row * BP + j] = f2bf(t * msk_s[row]);
                    }
                }
            }
        }
        if (tid < 128) qss_s[tid] = 0.0f;
    }
    __syncthreads();

    // ---------------- Attention layers ----------------
    const float tinv = 0.08838834764831845f;  // 1/sqrt(128)
    const int qt = wid >> 1;   // core pair: q-tile
    const int hh = wid & 1;    // core pair: half index
    const int q  = qt * 16 + l15;

    for (int l = 0; l < 2; ++l){
        // ===== A1 (balanced, raw store): each wave = 1 full K-or-V job
        //       (store raw, publish scale) + 1 half raw-Q job (same tile) ====
        {
            const int t = wid & 7;
            bf16x8 ag[4];
            #pragma unroll
            for (int ks = 0; ks < 4; ++ks)
                ag[ks] = *(const bf16x8*)&g16[(t*16 + l15) * BP + ks*32 + lg4 * 8];
            if (wid < 8){
                // K tile t: store raw K; publish kss = tinv*rsqrt(rowsum)
                float sq[4] = {0.f, 0.f, 0.f, 0.f};
                #pragma unroll
                for (int nt = 0; nt < 8; ++nt){
                    f32x4 C = (f32x4){0.f, 0.f, 0.f, 0.f};
                    #pragma unroll
                    for (int ks = 0; ks < 4; ++ks){
                        bf16x8 b = *(const bf16x8*)(wsb + (size_t)(((l*3+1)*8+nt)*4+ks) * 512 + lane * 8);
                        C = __builtin_amdgcn_mfma_f32_16x16x32_bf16(ag[ks], b, C, 0, 0, 0);
                    }
                    const float bias = bk[l * ADIM + nt*16 + l15];
                    #pragma unroll
                    for (int r = 0; r < 4; ++r){
                        const float v = C[r] + bias;
                        kn_s[(t*16 + lg4*4 + r) * BP + nt*16 + l15] = f2bf(v);
                        sq[r] = fmaf(v, v, sq[r]);
                    }
                }
                #pragma unroll
                for (int r = 0; r < 4; ++r){
                    const float s = red16(sq[r]);
                    if (l15 == 0) kss_s[t*16 + lg4*4 + r] = tinv * rsqrtf(fmaxf(s, 1e-24f));
                }
            } else {
                // V tile t: store raw V^T; publish vss = swm_k*rsqrt(rowsum)
                float sq[4] = {0.f, 0.f, 0.f, 0.f};
                #pragma unroll
                for (int nt = 0; nt < 8; ++nt){
                    f32x4 C = (f32x4){0.f, 0.f, 0.f, 0.f};
                    #pragma unroll
                    for (int ks = 0; ks < 4; ++ks){
                        bf16x8 b = *(const bf16x8*)(wsb + (size_t)(((l*3+2)*8+nt)*4+ks) * 512 + lane * 8);
                        C = __builtin_amdgcn_mfma_f32_16x16x32_bf16(ag[ks], b, C, 0, 0, 0);
                    }
                    const float bias = bv[l * ADIM + nt*16 + l15];
                    float v0 = C[0] + bias, v1 = C[1] + bias;
                    float v2 = C[2] + bias, v3 = C[3] + bias;
                    sq[0] = fmaf(v0, v0, sq[0]); sq[1] = fmaf(v1, v1, sq[1]);
                    sq[2] = fmaf(v2, v2, sq[2]); sq[3] = fmaf(v3, v3, sq[3]);
                    *(uint2*)&vT_s[(nt*16 + l15) * BP + t*16 + lg4*4] =
                        make_uint2(cvtpk(v0, v1), cvtpk(v2, v3));
                }
                #pragma unroll
                for (int r = 0; r < 4; ++r){
                    const int k = t*16 + lg4*4 + r;
                    const float s = red16(sq[r]);
                    if (l15 == 0) vss_s[k] = swm_s[k] * rsqrtf(fmaxf(s, 1e-24f));
                }
            }
            __builtin_amdgcn_sched_barrier(0);
            // Half-width raw-Q job on the SAME tile t, half hq = wid>>3
            {
                const int hq = wid >> 3;
                float sq2[4] = {0.f, 0.f, 0.f, 0.f};
                #pragma unroll
                for (int u = 0; u < 4; ++u){
                    const int nt = hq*4 + u;
                    f32x4 C = (f32x4){0.f, 0.f, 0.f, 0.f};
                    #pragma unroll
                    for (int ks = 0; ks < 4; ++ks){
                        bf16x8 b = *(const bf16x8*)(wsb + (size_t)(((l*3+0)*8+nt)*4+ks) * 512 + lane * 8);
                        C = __builtin_amdgcn_mfma_f32_16x16x32_bf16(ag[ks], b, C, 0, 0, 0);
                    }
                    const float bias = bq[l * ADIM + nt*16 + l15];
                    #pragma unroll
                    for (int r = 0; r < 4; ++r){
                        const float v = C[r] + bias;
                        buf1[(t*16 + lg4*4 + r) * BP + nt*16 + l15] = f2bf(v);
                        sq2[r] = fmaf(v, v, sq2[r]);
                    }
                }
                #pragma unroll
                for (int r = 0; r < 4; ++r){
                    const float s = red16(sq2[r]);
                    if (l15 == 0) atomicAdd(&qss_s[t*16 + lg4*4 + r], s);
                }
            }
        }
        __syncthreads();  // B1: Qraw, Kraw, Vraw^T, qss/kss/vss ready

        // ===== Core1: scores half + gate via MFMA; consumer-side scales ======
        unsigned int pw0[4], pw1[4];
        float tot;
        {
            bf16x8 bqf[4];
            #pragma unroll
            for (int ks = 0; ks < 4; ++ks)
                bqf[ks] = *(const bf16x8*)&buf1[(qt*16 + l15) * BP + ks*32 + lg4 * 8];
            bf16x8 bgq = *(const bf16x8*)&rh16[(qt*16 + l15) * RHP + lg4 * 8];
            f32x4 Cs[4];
            #pragma unroll
            for (int t = 0; t < 4; ++t) Cs[t] = (f32x4){0.f, 0.f, 0.f, 0.f};
            #pragma unroll
            for (int t = 0; t < 4; ++t)
                #pragma unroll
                for (int ks = 0; ks < 4; ++ks){
                    bf16x8 a = *(const bf16x8*)&kn_s[((hh*4+t)*16 + l15) * BP + ks*32 + lg4 * 8];
                    Cs[t] = __builtin_amdgcn_mfma_f32_16x16x32_bf16(a, bqf[ks], Cs[t], 0, 0, 0);
                }
            const float qi = rsqrtf(fmaxf(qss_s[q], 1e-24f));
            tot = 0.f;
            #pragma unroll
            for (int t = 0; t < 4; ++t){
                const int kb = (hh*4+t)*16 + lg4*4;
                // gate tile: G[r] = rhat_k . rhat_q  (col=q, row=k) — one MFMA
                bf16x8 agk = *(const bf16x8*)&rh16[((hh*4+t)*16 + l15) * RHP + lg4 * 8];
                f32x4 G = (f32x4){0.f, 0.f, 0.f, 0.f};
                G = __builtin_amdgcn_mfma_f32_16x16x32_bf16(agk, bgq, G, 0, 0, 0);
                const float4 ks4 = *(const float4*)&kss_s[kb];
                const float4 vs4 = *(const float4*)&vss_s[kb];
                float p[4];
                #pragma unroll
                for (int r = 0; r < 4; ++r){
                    const float e = __expf(Cs[t][r] * qi * ((const float*)&ks4)[r]) * msk_s[kb + r];
                    tot += e;
                    p[r] = e * G[r] * ((const float*)&vs4)[r];
                }
                pw0[t] = cvtpk(p[0], p[1]);
                pw1[t] = cvtpk(p[2], p[3]);
            }
            tot += __shfl_xor(tot, 16, 64);
            tot += __shfl_xor(tot, 32, 64);
        }
        __syncthreads();  // B2: all Q/K reads done; buf1/kn rows reusable

        // ===== Core2: publish P~ (= e*gate*vss) and psum =====
        #pragma unroll
        for (int t = 0; t < 4; ++t)
            *(uint2*)&buf1[(qt*16 + l15) * BP + (hh*4+t)*16 + lg4*4] = make_uint2(pw0[t], pw1[t]);
        if (lg4 == 0) psum_s[q * 2 + hh] = tot;
        __syncthreads();  // B3: P~, psum visible

        // ===== Core3: PV half; apply rsum to O'; publish O' =====
        {
            bf16x8 bpf[4];
            #pragma unroll
            for (int ks = 0; ks < 4; ++ks)
                bpf[ks] = *(const bf16x8*)&buf1[(qt*16 + l15) * BP + ks*32 + lg4 * 8];
            f32x4 Co[4];
            #pragma unroll
            for (int t = 0; t < 4; ++t) Co[t] = (f32x4){0.f, 0.f, 0.f, 0.f};
            #pragma unroll
            for (int t = 0; t < 4; ++t)
                #pragma unroll
                for (int ks = 0; ks < 4; ++ks){
                    bf16x8 a = *(const bf16x8*)&vT_s[((hh*4+t)*16 + l15) * BP + ks*32 + lg4 * 8];
                    Co[t] = __builtin_amdgcn_mfma_f32_16x16x32_bf16(a, bpf[ks], Co[t], 0, 0, 0);
                }
            const float totq = psum_s[q * 2] + psum_s[q * 2 + 1];
            const float rsum = (totq > 0.0f) ? swm_s[q] / totq : 0.0f;
            #pragma unroll
            for (int t = 0; t < 4; ++t){
                const unsigned int lo = cvtpk(Co[t][0] * rsum, Co[t][1] * rsum);
                const unsigned int hi = cvtpk(Co[t][2] * rsum, Co[t][3] * rsum);
                *(uint2*)&kn_s[(qt*16 + l15) * BP + (hh*4+t)*16 + lg4*4] = make_uint2(lo, hi);
            }
        }
        __syncthreads();  // B4: O' visible

        // ===== Core4: out-proj half + LN partials =====
        float val[4][4];
        {
            bf16x8 bof[4];
            #pragma unroll
            for (int ks = 0; ks < 4; ++ks)
                bof[ks] = *(const bf16x8*)&kn_s[(qt*16 + l15) * BP + ks*32 + lg4 * 8];
            const float* BO = bo + l * MDIM;
            float sv = 0.f, sv2 = 0.f;
            #pragma unroll
            for (int t = 0; t < 4; ++t){
                const int jt = hh*4 + t;
                f32x4 Cf = (f32x4){0.f, 0.f, 0.f, 0.f};
                #pragma unroll
                for (int ks = 0; ks < 4; ++ks){
                    bf16x8 a = *(const bf16x8*)(wsb + (size_t)(192 + (l*8+jt)*4 + ks) * 512 + lane * 8);
                    Cf = __builtin_amdgcn_mfma_f32_16x16x32_bf16(a, bof[ks], Cf, 0, 0, 0);
                }
                const bool jok = (jt < 6) || (jt == 6 && lg4 == 0);
                float4 BO4 = jok ? *(const float4*)&BO[jt*16 + lg4*4] : make_float4(0,0,0,0);
                #pragma unroll
                for (int r = 0; r < 4; ++r){
                    const float v = Cf[r] + ((const float*)&BO4)[r];
                    val[t][r] = v;
                    if (jok){ sv += v; sv2 += v * v; }
                }
            }
            sv  += __shfl_xor(sv, 16, 64);  sv  += __shfl_xor(sv, 32, 64);
            sv2 += __shfl_xor(sv2, 16, 64); sv2 += __shfl_xor(sv2, 32, 64);
            if (lg4 == 0){
                lnp_s[q * 4 + hh * 2 + 0] = sv;
                lnp_s[q * 4 + hh * 2 + 1] = sv2;
            }
        }
        __syncthreads();  // B5: LN partials visible

        // ===== Core5: LayerNorm apply + residual into g16 (own jt half) =====
        {
            const float* LG = lng + l * MDIM;
            const float* LB = lnb + l * MDIM;
            const float svt  = lnp_s[q * 4 + 0] + lnp_s[q * 4 + 2];
            const float sv2t = lnp_s[q * 4 + 1] + lnp_s[q * 4 + 3];
            const float mu   = svt * 0.01f;
            const float var  = sv2t * 0.01f - mu * mu;
            const float rstd = rsqrtf(var + 1e-5f);
            if (q < NNEI){
                #pragma unroll
                for (int t = 0; t < 4; ++t){
                    const int jt = hh*4 + t;
                    const bool jok = (jt < 6) || (jt == 6 && lg4 == 0);
                    if (jok){
                        const int jb = jt*16 + lg4*4;
                        const float4 LG4 = *(const float4*)&LG[jb];
                        const float4 LB4 = *(const float4*)&LB[jb];
                        uint2 old = *(const uint2*)&g16[q * BP + jb];
                        float nv[4];
                        nv[0] = bf2f((unsigned short)(old.x & 0xffffu))  + (val[t][0] - mu) * rstd * LG4.x + LB4.x;
                        nv[1] = bf2f((unsigned short)(old.x >> 16))      + (val[t][1] - mu) * rstd * LG4.y + LB4.y;
                        nv[2] = bf2f((unsigned short)(old.y & 0xffffu))  + (val[t][2] - mu) * rstd * LG4.z + LB4.z;
                        nv[3] = bf2f((unsigned short)(old.y >> 16))      + (val[t][3] - mu) * rstd * LG4.w + LB4.w;
                        uint2 nw;
                        nw.x = cvtpk(nv[0], nv[1]);
                        nw.y = cvtpk(nv[2], nv[3]);
                        *(uint2*)&g16[q * BP + jb] = nw;
                    }
                }
            }
            if (tid < 128) qss_s[tid] = 0.0f;   // reset for next layer's A1
        }
        __syncthreads();  // B6: end of layer
    }

    // ---------------- Final: gr = env^T g / NNEI ; d = gr^T gr[:, :16] -------
    for (int idx = tid; idx < 4 * MDIM; idx += 1024){
        const int c = idx / MDIM, mm = idx - c * MDIM;
        float a = 0.0f;
        for (int k = 0; k < NNEI; ++k)
            a = fmaf(env_s[k * 4 + c], bf2f(g16[k * BP + mm]), a);
        gr_s[c * MDIM + mm] = a * (1.0f / 120.0f);
    }
    __syncthreads();

    float* outp = out + (size_t)n * OUTD;
    for (int idx = tid; idx < MDIM * 16; idx += 1024){
        const int mm = idx >> 4, aa = idx & 15;
        float acc = 0.0f;
        #pragma unroll
        for (int c = 0; c < 4; ++c)
            acc = fmaf(gr_s[c * MDIM + mm], gr_s[c * MDIM + aa], acc);
        outp[idx] = acc;
    }
    if (tid < 8) outp[1600 + tid] = tebd_s[ta_sh * 8 + tid];
}

extern "C" void kernel_launch(void* const* d_in, const int* in_sizes, int n_in,
                              void* d_out, int out_size, void* d_ws, size_t ws_size,
                              hipStream_t stream) {
    const float* rij   = (const float*)d_in[0];
    const void*  nmask = d_in[1];
    const int*   atype = (const int*)d_in[2];
    const int*   ntype = (const int*)d_in[3];
    const float* tebd  = (const float*)d_in[4];
    const float* ew0 = (const float*)d_in[5];
    const float* eb0 = (const float*)d_in[6];
    const float* ew1 = (const float*)d_in[7];
    const float* eb1 = (const float*)d_in[8];
    const float* ew2 = (const float*)d_in[9];
    const float* eb2 = (const float*)d_in[10];
    const float* wq = (const float*)d_in[11];
    const float* bq = (const float*)d_in[12];
    const float* wk = (const float*)d_in[13];
    const float* bk = (const float*)d_in[14];
    const float* wv = (const float*)d_in[15];
    const float* bv = (const float*)d_in[16];
    const float* wo = (const float*)d_in[17];
    const float* bo = (const float*)d_in[18];
    const float* lng = (const float*)d_in[19];
    const float* lnb = (const float*)d_in[20];
    float* out = (float*)d_out;
    int* flag = (int*)d_ws;
    unsigned short* wsb = (unsigned short*)((char*)d_ws + 256);

    detect_mask_kernel<<<1, 64, 0, stream>>>((const unsigned char*)nmask, flag);
    prep_weights<<<276, 64, 0, stream>>>(wq, wk, wv, wo, ew2, ew0, ew1, wsb);
    dpa1_kernel<<<4096, 1024, 0, stream>>>(rij, nmask, atype, ntype, tebd,
                                           eb0, eb1, eb2,
                                           bq, bk, bv, bo, lng, lnb,
                                           out, flag, wsb);
}

// Round 18
// 676.183 us; speedup vs baseline: 1.1945x; 1.0401x over previous
//
#include <hip/hip_runtime.h>

// DescrptDPA1 on gfx950 — R18: R17 + (1) final gr-contraction via MFMA
// (envT staged bf16 in dead buf1; kills the 8-way-conflicted 120-deep scalar
// loop), (2) qss atomics -> direct 2-slot stores, (3) rhat_s deleted (dead).
// NF=1, NLOC=4096, NNEI=120, TEBD=8, NTYPES=4, M=100, ATTN=128, NLAYER=2, AXIS=16.

#define NNEI 120
#define MDIM 100
#define ADIM 128
#define BP   136   // bf16 pitch (272B rows; 68 dw = 4 mod 32 banks, 16B aligned)
#define H2P  72    // bf16 pitch for h2 staging
#define XP   40    // bf16 pitch for x / h1 staging (80B rows, 16B aligned)
#define RHP  40    // bf16 pitch for rhat staging
#define OUTD 1608

typedef __attribute__((ext_vector_type(8))) short bf16x8;
typedef __attribute__((ext_vector_type(4))) float f32x4;

__device__ __forceinline__ float bf2f(unsigned short u){
    return __uint_as_float(((unsigned int)u) << 16);
}
__device__ __forceinline__ unsigned short f2bf(float f){
    unsigned int x = __float_as_uint(f);
    return (unsigned short)((x + 0x7fffu + ((x >> 16) & 1u)) >> 16);
}
__device__ __forceinline__ unsigned int cvtpk(float lo, float hi){
    unsigned int r;
    asm("v_cvt_pk_bf16_f32 %0, %1, %2" : "=v"(r) : "v"(lo), "v"(hi));
    return r;
}
__device__ __forceinline__ float ftanh(float x){
    return 1.0f - 2.0f / (__expf(2.0f * x) + 1.0f);
}
__device__ __forceinline__ float red16(float v){
    v += __shfl_xor(v, 1, 64); v += __shfl_xor(v, 2, 64);
    v += __shfl_xor(v, 4, 64); v += __shfl_xor(v, 8, 64);
    return v;
}

// nmask storage detection: 1 = int32 {0,1}, 2 = f32 {0.0,1.0}, 0 = byte bool
__global__ void detect_mask_kernel(const unsigned char* __restrict__ p,
                                   int* __restrict__ flag){
    if (blockIdx.x == 0 && threadIdx.x == 0){
        const unsigned int* u = (const unsigned int*)p;
        int alli = 1, allf = 1;
        for (int i = 0; i < 64; ++i){
            unsigned int w = u[i];
            if (!(w == 0u || w == 1u)) alli = 0;
            if (!(w == 0u || w == 0x3f800000u)) allf = 0;
        }
        flag[0] = alli ? 1 : (allf ? 2 : 0);
    }
}

// Pack weights (bf16). Frag = [64 lanes][8 bf16] = 1024B.
// QKV B-frags: fid = ((l*3+mat)*8+nt)*4+ks            (0..191)
// WO A-frags:  fid = 192 + (l*8+jt)*4+ks              (192..255, jt=7 zero)
// ew2 B-frags: fid = 256 + nt*2 + ks                  (256..269)
// ew0 B-frags: fid = 270 + nt   (nt=0,1; K=17 pad 32) (270..271)
// ew1 B-frags: fid = 272 + nt   (nt=0..3; K=25 pad 32)(272..275)
__global__ void prep_weights(const float* __restrict__ wq, const float* __restrict__ wk,
                             const float* __restrict__ wv, const float* __restrict__ wo,
                             const float* __restrict__ ew2, const float* __restrict__ ew0,
                             const float* __restrict__ ew1,
                             unsigned short* __restrict__ wsb){
    const int fid = blockIdx.x;
    const int lane = threadIdx.x;  // 64
    unsigned short* dst = wsb + (size_t)fid * 512 + lane * 8;
    if (fid < 192){
        const int l = fid / 96, rem = fid % 96, mat = rem / 32;
        const int r2 = rem % 32, nt = r2 / 4, ks = r2 % 4;
        const float* W = (mat == 0 ? wq : mat == 1 ? wk : wv) + l * MDIM * ADIM;
        const int nn = nt * 16 + (lane & 15);
        const int k0 = ks * 32 + (lane >> 4) * 8;
        #pragma unroll
        for (int i = 0; i < 8; ++i){
            const int kk = k0 + i;
            dst[i] = (kk < MDIM) ? f2bf(W[kk * ADIM + nn]) : (unsigned short)0;
        }
    } else if (fid < 256){
        const int f2 = fid - 192, l = f2 / 32, rem = f2 % 32, jt = rem / 4, ks = rem % 4;
        const float* W = wo + l * ADIM * MDIM;
        const int j = jt * 16 + (lane & 15);
        const int d0 = ks * 32 + (lane >> 4) * 8;
        #pragma unroll
        for (int i = 0; i < 8; ++i)
            dst[i] = (j < MDIM) ? f2bf(W[(d0 + i) * MDIM + j]) : (unsigned short)0;
    } else if (fid < 270){
        const int f3 = fid - 256, nt = f3 >> 1, ks = f3 & 1;
        const int nn = nt * 16 + (lane & 15);
        const int k0 = ks * 32 + (lane >> 4) * 8;
        #pragma unroll
        for (int i = 0; i < 8; ++i){
            const int kk = k0 + i;
            dst[i] = (kk < 50 && nn < MDIM) ? f2bf(ew2[kk * MDIM + nn]) : (unsigned short)0;
        }
    } else if (fid < 272){
        const int nt = fid - 270;
        const int nn = nt * 16 + (lane & 15);
        const int k0 = (lane >> 4) * 8;
        #pragma unroll
        for (int i = 0; i < 8; ++i){
            const int kk = k0 + i;
            dst[i] = (kk < 17 && nn < 25) ? f2bf(ew0[kk * 25 + nn]) : (unsigned short)0;
        }
    } else {
        const int nt = fid - 272;
        const int nn = nt * 16 + (lane & 15);
        const int k0 = (lane >> 4) * 8;
        #pragma unroll
        for (int i = 0; i < 8; ++i){
            const int kk = k0 + i;
            dst[i] = (kk < 25 && nn < 50) ? f2bf(ew1[kk * 50 + nn]) : (unsigned short)0;
        }
    }
}

__global__ __launch_bounds__(1024) void dpa1_kernel(
    const float* __restrict__ rij, const void* __restrict__ nmask,
    const int* __restrict__ atype, const int* __restrict__ ntype,
    const float* __restrict__ tebd,
    const float* __restrict__ eb0, const float* __restrict__ eb1,
    const float* __restrict__ eb2,
    const float* __restrict__ bq, const float* __restrict__ bk,
    const float* __restrict__ bv, const float* __restrict__ bo,
    const float* __restrict__ lng, const float* __restrict__ lnb,
    float* __restrict__ out, const int* __restrict__ flagp,
    const unsigned short* __restrict__ wsb)
{
    __shared__ __align__(16) unsigned short g16[128 * BP];   // bf16 g master
    __shared__ __align__(16) unsigned short buf1[128 * BP];  // h2 -> Qraw -> P~ -> envT
    __shared__ __align__(16) unsigned short kn_s[128 * BP];  // x -> Kraw -> O'
    __shared__ __align__(16) unsigned short vT_s[128 * BP];  // h1 -> Vraw^T
    __shared__ __align__(16) unsigned short rh16[128 * RHP]; // bf16 rhat (K=32 zero-pad)
    __shared__ float psum_s[256];
    __shared__ float lnp_s[512];
    __shared__ float qss2_s[256];         // |Q row|^2 per (half, row)
    __shared__ __align__(16) float kss_s[128];  // tinv * rsqrt(|K row|^2)
    __shared__ __align__(16) float vss_s[128];  // swm_k * rsqrt(|V row|^2)
    __shared__ __align__(16) float env_s[128 * 4];
    __shared__ __align__(16) float swm_s[128];
    __shared__ __align__(16) float msk_s[128];
    __shared__ float tebd_s[32];
    __shared__ float gr_s[4 * MDIM];
    __shared__ int ta_sh;

    const int n    = blockIdx.x;
    const int tid  = threadIdx.x;
    const int lane = tid & 63;
    const int wid  = tid >> 6;
    const int flag = flagp[0];
    const int l15  = lane & 15;
    const int lg4  = lane >> 4;

    if (tid < 32) tebd_s[tid] = tebd[tid];
    if (tid == 0) ta_sh = atype[n];

    // ---------------- P-geom: geometry + x/rhat staging + zero g16 -----------
    {
        unsigned int* z0 = (unsigned int*)g16;
        for (int i = tid; i < 128 * (BP/2); i += 1024) z0[i] = 0;
    }
    if (tid < 128){
        const int k = tid;
        unsigned short xr[2 * XP];
        #pragma unroll
        for (int i = 0; i < 2 * XP; ++i) xr[i] = 0;
        unsigned short rr[32];
        #pragma unroll
        for (int i = 0; i < 32; ++i) rr[i] = 0;
        if (k < NNEI){
            const int base = n * NNEI + k;
            const float rx = rij[base * 3 + 0];
            const float ry = rij[base * 3 + 1];
            const float rz = rij[base * 3 + 2];
            const float r  = sqrtf(rx * rx + ry * ry + rz * rz);
            float mval;
            if (flag == 1)      mval = (((const int*)nmask)[base] != 0) ? 1.0f : 0.0f;
            else if (flag == 2) mval = ((const float*)nmask)[base];
            else                mval = (((const unsigned char*)nmask)[base] != 0) ? 1.0f : 0.0f;
            float uu = (r - 0.5f) * (1.0f / 5.5f);
            uu = fminf(fmaxf(uu, 0.0f), 1.0f);
            const float sw   = uu * uu * uu * (-6.0f * uu * uu + 15.0f * uu - 10.0f) + 1.0f;
            const float invr = 1.0f / r;
            const float sr   = sw * invr * mval;
            const float hx = rx * invr, hy = ry * invr, hz = rz * invr;
            env_s[k * 4 + 0] = sr;
            env_s[k * 4 + 1] = sr * hx;
            env_s[k * 4 + 2] = sr * hy;
            env_s[k * 4 + 3] = sr * hz;
            swm_s[k] = sw * mval;
            msk_s[k] = mval;
            const int tn = ntype[base] * 8;
            const int tc = atype[n] * 8;
            xr[0] = f2bf(sr);
            #pragma unroll
            for (int i = 0; i < 8; ++i){
                xr[1 + i] = f2bf(tebd[tn + i]);
                xr[9 + i] = f2bf(tebd[tc + i]);
            }
            rr[0] = f2bf(hx); rr[1] = f2bf(hy); rr[2] = f2bf(hz);
        } else {
            env_s[k*4+0] = env_s[k*4+1] = env_s[k*4+2] = env_s[k*4+3] = 0.0f;
            swm_s[k] = 0.0f; msk_s[k] = 0.0f;
        }
        #pragma unroll
        for (int c = 0; c < 5; ++c)
            *(uint4*)&kn_s[k * XP + c * 8] = *(const uint4*)&xr[c * 8];
        #pragma unroll
        for (int c = 0; c < 4; ++c)
            *(uint4*)&rh16[k * RHP + c * 8] = *(const uint4*)&rr[c * 8];
    }
    __syncthreads();

    // ---------------- e1 (MFMA): h1 = tanh(x @ ew0 + eb0) -> vT_s bf16 -------
    {
        const int mt = wid >> 1, nt = wid & 1;   // 16 jobs, 1 per wave
        bf16x8 a = *(const bf16x8*)&kn_s[(mt*16 + l15) * XP + lg4 * 8];
        bf16x8 b = *(const bf16x8*)(wsb + (size_t)(270 + nt) * 512 + lane * 8);
        f32x4 C = (f32x4){0.f, 0.f, 0.f, 0.f};
        C = __builtin_amdgcn_mfma_f32_16x16x32_bf16(a, b, C, 0, 0, 0);
        const int j = nt * 16 + l15;
        const float ebj = (j < 25) ? eb0[j] : 0.0f;
        #pragma unroll
        for (int r = 0; r < 4; ++r){
            const int row = mt * 16 + lg4 * 4 + r;
            const float v = (row < NNEI && j < 25) ? ftanh(C[r] + ebj) : 0.0f;
            vT_s[row * XP + j] = f2bf(v);
        }
    }
    __syncthreads();

    // ---------------- e2 (MFMA): h2 = tanh(h1 @ ew1 + eb1) + [h1,h1] -> buf1 --
    {
        for (int jb = wid; jb < 32; jb += 16){   // 2 jobs per wave
            const int mt = jb >> 2, nt = jb & 3;
            bf16x8 a = *(const bf16x8*)&vT_s[(mt*16 + l15) * XP + lg4 * 8];
            bf16x8 b = *(const bf16x8*)(wsb + (size_t)(272 + nt) * 512 + lane * 8);
            f32x4 C = (f32x4){0.f, 0.f, 0.f, 0.f};
            C = __builtin_amdgcn_mfma_f32_16x16x32_bf16(a, b, C, 0, 0, 0);
            const int j2 = nt * 16 + l15;
            const float ebj = (j2 < 50) ? eb1[j2] : 0.0f;
            const int jr = (j2 >= 25) ? j2 - 25 : j2;
            #pragma unroll
            for (int r = 0; r < 4; ++r){
                const int row = mt * 16 + lg4 * 4 + r;
                float v = 0.0f;
                if (row < NNEI && j2 < 50){
                    const float h1d = bf2f(vT_s[row * XP + jr]);
                    v = ftanh(C[r] + ebj) + h1d;
                }
                buf1[row * H2P + j2] = f2bf(v);
            }
        }
    }
    __syncthreads();

    // ---------------- e3: g = (tanh(h2 @ ew2 + eb2) + [h2,h2]) * m  (MFMA) ---
    {
        for (int job = wid; job < 56; job += 16){
            const int mt = job / 7, nt = job - mt * 7;
            bf16x8 a0 = *(const bf16x8*)&buf1[(mt*16 + l15) * H2P + 0*32 + lg4 * 8];
            bf16x8 a1 = *(const bf16x8*)&buf1[(mt*16 + l15) * H2P + 1*32 + lg4 * 8];
            bf16x8 b0 = *(const bf16x8*)(wsb + (size_t)(256 + nt*2 + 0) * 512 + lane * 8);
            bf16x8 b1 = *(const bf16x8*)(wsb + (size_t)(256 + nt*2 + 1) * 512 + lane * 8);
            f32x4 C = (f32x4){0.f, 0.f, 0.f, 0.f};
            C = __builtin_amdgcn_mfma_f32_16x16x32_bf16(a0, b0, C, 0, 0, 0);
            C = __builtin_amdgcn_mfma_f32_16x16x32_bf16(a1, b1, C, 0, 0, 0);
            const int j = nt * 16 + l15;
            if (j < MDIM){
                const float ebj = eb2[j];
                const int jr = (j >= 50) ? j - 50 : j;
                #pragma unroll
                for (int r = 0; r < 4; ++r){
                    const int row = mt * 16 + lg4 * 4 + r;
                    if (row < NNEI){
                        const float h2d = bf2f(buf1[row * H2P + jr]);
                        const float t = ftanh(C[r] + ebj) + h2d;
                        g16[row * BP + j] = f2bf(t * msk_s[row]);
                    }
                }
            }
        }
    }
    __syncthreads();

    // ---------------- Attention layers ----------------
    const float tinv = 0.08838834764831845f;  // 1/sqrt(128)
    const int qt = wid >> 1;   // core pair: q-tile
    const int hh = wid & 1;    // core pair: half index
    const int q  = qt * 16 + l15;

    for (int l = 0; l < 2; ++l){
        // ===== A1 (balanced, raw store): each wave = 1 full K-or-V job
        //       (store raw, publish scale) + 1 half raw-Q job (same tile) ====
        {
            const int t = wid & 7;
            bf16x8 ag[4];
            #pragma unroll
            for (int ks = 0; ks < 4; ++ks)
                ag[ks] = *(const bf16x8*)&g16[(t*16 + l15) * BP + ks*32 + lg4 * 8];
            if (wid < 8){
                // K tile t: store raw K; publish kss = tinv*rsqrt(rowsum)
                float sq[4] = {0.f, 0.f, 0.f, 0.f};
                #pragma unroll
                for (int nt = 0; nt < 8; ++nt){
                    f32x4 C = (f32x4){0.f, 0.f, 0.f, 0.f};
                    #pragma unroll
                    for (int ks = 0; ks < 4; ++ks){
                        bf16x8 b = *(const bf16x8*)(wsb + (size_t)(((l*3+1)*8+nt)*4+ks) * 512 + lane * 8);
                        C = __builtin_amdgcn_mfma_f32_16x16x32_bf16(ag[ks], b, C, 0, 0, 0);
                    }
                    const float bias = bk[l * ADIM + nt*16 + l15];
                    #pragma unroll
                    for (int r = 0; r < 4; ++r){
                        const float v = C[r] + bias;
                        kn_s[(t*16 + lg4*4 + r) * BP + nt*16 + l15] = f2bf(v);
                        sq[r] = fmaf(v, v, sq[r]);
                    }
                }
                #pragma unroll
                for (int r = 0; r < 4; ++r){
                    const float s = red16(sq[r]);
                    if (l15 == 0) kss_s[t*16 + lg4*4 + r] = tinv * rsqrtf(fmaxf(s, 1e-24f));
                }
            } else {
                // V tile t: store raw V^T; publish vss = swm_k*rsqrt(rowsum)
                float sq[4] = {0.f, 0.f, 0.f, 0.f};
                #pragma unroll
                for (int nt = 0; nt < 8; ++nt){
                    f32x4 C = (f32x4){0.f, 0.f, 0.f, 0.f};
                    #pragma unroll
                    for (int ks = 0; ks < 4; ++ks){
                        bf16x8 b = *(const bf16x8*)(wsb + (size_t)(((l*3+2)*8+nt)*4+ks) * 512 + lane * 8);
                        C = __builtin_amdgcn_mfma_f32_16x16x32_bf16(ag[ks], b, C, 0, 0, 0);
                    }
                    const float bias = bv[l * ADIM + nt*16 + l15];
                    float v0 = C[0] + bias, v1 = C[1] + bias;
                    float v2 = C[2] + bias, v3 = C[3] + bias;
                    sq[0] = fmaf(v0, v0, sq[0]); sq[1] = fmaf(v1, v1, sq[1]);
                    sq[2] = fmaf(v2, v2, sq[2]); sq[3] = fmaf(v3, v3, sq[3]);
                    *(uint2*)&vT_s[(nt*16 + l15) * BP + t*16 + lg4*4] =
                        make_uint2(cvtpk(v0, v1), cvtpk(v2, v3));
                }
                #pragma unroll
                for (int r = 0; r < 4; ++r){
                    const int k = t*16 + lg4*4 + r;
                    const float s = red16(sq[r]);
                    if (l15 == 0) vss_s[k] = swm_s[k] * rsqrtf(fmaxf(s, 1e-24f));
                }
            }
            __builtin_amdgcn_sched_barrier(0);
            // Half-width raw-Q job on the SAME tile t, half hq = wid>>3
            {
                const int hq = wid >> 3;
                float sq2[4] = {0.f, 0.f, 0.f, 0.f};
                #pragma unroll
                for (int u = 0; u < 4; ++u){
                    const int nt = hq*4 + u;
                    f32x4 C = (f32x4){0.f, 0.f, 0.f, 0.f};
                    #pragma unroll
                    for (int ks = 0; ks < 4; ++ks){
                        bf16x8 b = *(const bf16x8*)(wsb + (size_t)(((l*3+0)*8+nt)*4+ks) * 512 + lane * 8);
                        C = __builtin_amdgcn_mfma_f32_16x16x32_bf16(ag[ks], b, C, 0, 0, 0);
                    }
                    const float bias = bq[l * ADIM + nt*16 + l15];
                    #pragma unroll
                    for (int r = 0; r < 4; ++r){
                        const float v = C[r] + bias;
                        buf1[(t*16 + lg4*4 + r) * BP + nt*16 + l15] = f2bf(v);
                        sq2[r] = fmaf(v, v, sq2[r]);
                    }
                }
                #pragma unroll
                for (int r = 0; r < 4; ++r){
                    const float s = red16(sq2[r]);
                    if (l15 == 0) qss2_s[hq * 128 + t*16 + lg4*4 + r] = s;
                }
            }
        }
        __syncthreads();  // B1: Qraw, Kraw, Vraw^T, qss/kss/vss ready

        // ===== Core1: scores half + gate via MFMA; consumer-side scales ======
        unsigned int pw0[4], pw1[4];
        float tot;
        {
            bf16x8 bqf[4];
            #pragma unroll
            for (int ks = 0; ks < 4; ++ks)
                bqf[ks] = *(const bf16x8*)&buf1[(qt*16 + l15) * BP + ks*32 + lg4 * 8];
            bf16x8 bgq = *(const bf16x8*)&rh16[(qt*16 + l15) * RHP + lg4 * 8];
            f32x4 Cs[4];
            #pragma unroll
            for (int t = 0; t < 4; ++t) Cs[t] = (f32x4){0.f, 0.f, 0.f, 0.f};
            #pragma unroll
            for (int t = 0; t < 4; ++t)
                #pragma unroll
                for (int ks = 0; ks < 4; ++ks){
                    bf16x8 a = *(const bf16x8*)&kn_s[((hh*4+t)*16 + l15) * BP + ks*32 + lg4 * 8];
                    Cs[t] = __builtin_amdgcn_mfma_f32_16x16x32_bf16(a, bqf[ks], Cs[t], 0, 0, 0);
                }
            const float qi = rsqrtf(fmaxf(qss2_s[q] + qss2_s[128 + q], 1e-24f));
            tot = 0.f;
            #pragma unroll
            for (int t = 0; t < 4; ++t){
                const int kb = (hh*4+t)*16 + lg4*4;
                bf16x8 agk = *(const bf16x8*)&rh16[((hh*4+t)*16 + l15) * RHP + lg4 * 8];
                f32x4 G = (f32x4){0.f, 0.f, 0.f, 0.f};
                G = __builtin_amdgcn_mfma_f32_16x16x32_bf16(agk, bgq, G, 0, 0, 0);
                const float4 ks4 = *(const float4*)&kss_s[kb];
                const float4 vs4 = *(const float4*)&vss_s[kb];
                float p[4];
                #pragma unroll
                for (int r = 0; r < 4; ++r){
                    const float e = __expf(Cs[t][r] * qi * ((const float*)&ks4)[r]) * msk_s[kb + r];
                    tot += e;
                    p[r] = e * G[r] * ((const float*)&vs4)[r];
                }
                pw0[t] = cvtpk(p[0], p[1]);
                pw1[t] = cvtpk(p[2], p[3]);
            }
            tot += __shfl_xor(tot, 16, 64);
            tot += __shfl_xor(tot, 32, 64);
        }
        __syncthreads();  // B2: all Q/K reads done; buf1/kn rows reusable

        // ===== Core2: publish P~ (= e*gate*vss) and psum =====
        #pragma unroll
        for (int t = 0; t < 4; ++t)
            *(uint2*)&buf1[(qt*16 + l15) * BP + (hh*4+t)*16 + lg4*4] = make_uint2(pw0[t], pw1[t]);
        if (lg4 == 0) psum_s[q * 2 + hh] = tot;
        __syncthreads();  // B3: P~, psum visible

        // ===== Core3: PV half; apply rsum to O'; publish O' =====
        {
            bf16x8 bpf[4];
            #pragma unroll
            for (int ks = 0; ks < 4; ++ks)
                bpf[ks] = *(const bf16x8*)&buf1[(qt*16 + l15) * BP + ks*32 + lg4 * 8];
            f32x4 Co[4];
            #pragma unroll
            for (int t = 0; t < 4; ++t) Co[t] = (f32x4){0.f, 0.f, 0.f, 0.f};
            #pragma unroll
            for (int t = 0; t < 4; ++t)
                #pragma unroll
                for (int ks = 0; ks < 4; ++ks){
                    bf16x8 a = *(const bf16x8*)&vT_s[((hh*4+t)*16 + l15) * BP + ks*32 + lg4 * 8];
                    Co[t] = __builtin_amdgcn_mfma_f32_16x16x32_bf16(a, bpf[ks], Co[t], 0, 0, 0);
                }
            const float totq = psum_s[q * 2] + psum_s[q * 2 + 1];
            const float rsum = (totq > 0.0f) ? swm_s[q] / totq : 0.0f;
            #pragma unroll
            for (int t = 0; t < 4; ++t){
                const unsigned int lo = cvtpk(Co[t][0] * rsum, Co[t][1] * rsum);
                const unsigned int hi = cvtpk(Co[t][2] * rsum, Co[t][3] * rsum);
                *(uint2*)&kn_s[(qt*16 + l15) * BP + (hh*4+t)*16 + lg4*4] = make_uint2(lo, hi);
            }
        }
        __syncthreads();  // B4: O' visible

        // ===== Core4: out-proj half + LN partials =====
        float val[4][4];
        {
            bf16x8 bof[4];
            #pragma unroll
            for (int ks = 0; ks < 4; ++ks)
                bof[ks] = *(const bf16x8*)&kn_s[(qt*16 + l15) * BP + ks*32 + lg4 * 8];
            const float* BO = bo + l * MDIM;
            float sv = 0.f, sv2 = 0.f;
            #pragma unroll
            for (int t = 0; t < 4; ++t){
                const int jt = hh*4 + t;
                f32x4 Cf = (f32x4){0.f, 0.f, 0.f, 0.f};
                #pragma unroll
                for (int ks = 0; ks < 4; ++ks){
                    bf16x8 a = *(const bf16x8*)(wsb + (size_t)(192 + (l*8+jt)*4 + ks) * 512 + lane * 8);
                    Cf = __builtin_amdgcn_mfma_f32_16x16x32_bf16(a, bof[ks], Cf, 0, 0, 0);
                }
                const bool jok = (jt < 6) || (jt == 6 && lg4 == 0);
                float4 BO4 = jok ? *(const float4*)&BO[jt*16 + lg4*4] : make_float4(0,0,0,0);
                #pragma unroll
                for (int r = 0; r < 4; ++r){
                    const float v = Cf[r] + ((const float*)&BO4)[r];
                    val[t][r] = v;
                    if (jok){ sv += v; sv2 += v * v; }
                }
            }
            sv  += __shfl_xor(sv, 16, 64);  sv  += __shfl_xor(sv, 32, 64);
            sv2 += __shfl_xor(sv2, 16, 64); sv2 += __shfl_xor(sv2, 32, 64);
            if (lg4 == 0){
                lnp_s[q * 4 + hh * 2 + 0] = sv;
                lnp_s[q * 4 + hh * 2 + 1] = sv2;
            }
        }
        __syncthreads();  // B5: LN partials visible

        // ===== Core5: LayerNorm apply + residual into g16 (own jt half) =====
        {
            const float* LG = lng + l * MDIM;
            const float* LB = lnb + l * MDIM;
            const float svt  = lnp_s[q * 4 + 0] + lnp_s[q * 4 + 2];
            const float sv2t = lnp_s[q * 4 + 1] + lnp_s[q * 4 + 3];
            const float mu   = svt * 0.01f;
            const float var  = sv2t * 0.01f - mu * mu;
            const float rstd = rsqrtf(var + 1e-5f);
            if (q < NNEI){
                #pragma unroll
                for (int t = 0; t < 4; ++t){
                    const int jt = hh*4 + t;
                    const bool jok = (jt < 6) || (jt == 6 && lg4 == 0);
                    if (jok){
                        const int jb = jt*16 + lg4*4;
                        const float4 LG4 = *(const float4*)&LG[jb];
                        const float4 LB4 = *(const float4*)&LB[jb];
                        uint2 old = *(const uint2*)&g16[q * BP + jb];
                        float nv[4];
                        nv[0] = bf2f((unsigned short)(old.x & 0xffffu))  + (val[t][0] - mu) * rstd * LG4.x + LB4.x;
                        nv[1] = bf2f((unsigned short)(old.x >> 16))      + (val[t][1] - mu) * rstd * LG4.y + LB4.y;
                        nv[2] = bf2f((unsigned short)(old.y & 0xffffu))  + (val[t][2] - mu) * rstd * LG4.z + LB4.z;
                        nv[3] = bf2f((unsigned short)(old.y >> 16))      + (val[t][3] - mu) * rstd * LG4.w + LB4.w;
                        uint2 nw;
                        nw.x = cvtpk(nv[0], nv[1]);
                        nw.y = cvtpk(nv[2], nv[3]);
                        *(uint2*)&g16[q * BP + jb] = nw;
                    }
                }
            }
        }
        __syncthreads();  // B6: end of layer
    }

    // ---------------- Final: gr = env^T g / NNEI (MFMA) ; d = gr^T gr[:,:16] --
    // stage envT bf16 into buf1 (dead): rows c=0..15 (c>=4 zero), cols k
    for (int idx = tid; idx < 16 * 128; idx += 1024){
        const int c = idx >> 7, k = idx & 127;
        buf1[c * BP + k] = (c < 4) ? f2bf(env_s[k * 4 + c]) : (unsigned short)0;
    }
    __syncthreads();
    if (wid < 7){
        const int nt = wid;
        bf16x8 ae[4];
        #pragma unroll
        for (int ks = 0; ks < 4; ++ks)
            ae[ks] = *(const bf16x8*)&buf1[l15 * BP + ks*32 + lg4 * 8];
        f32x4 C = (f32x4){0.f, 0.f, 0.f, 0.f};
        #pragma unroll
        for (int ks = 0; ks < 4; ++ks){
            unsigned short bw[8];
            #pragma unroll
            for (int i = 0; i < 8; ++i)
                bw[i] = g16[(ks*32 + lg4*8 + i) * BP + nt*16 + l15];
            bf16x8 b = *(const bf16x8*)bw;
            C = __builtin_amdgcn_mfma_f32_16x16x32_bf16(ae[ks], b, C, 0, 0, 0);
        }
        const int m = nt * 16 + l15;
        if (lg4 == 0 && m < MDIM){
            #pragma unroll
            for (int r = 0; r < 4; ++r)
                gr_s[r * MDIM + m] = C[r] * (1.0f / 120.0f);
        }
    }
    __syncthreads();

    float* outp = out + (size_t)n * OUTD;
    for (int idx = tid; idx < MDIM * 16; idx += 1024){
        const int mm = idx >> 4, aa = idx & 15;
        float acc = 0.0f;
        #pragma unroll
        for (int c = 0; c < 4; ++c)
            acc = fmaf(gr_s[c * MDIM + mm], gr_s[c * MDIM + aa], acc);
        outp[idx] = acc;
    }
    if (tid < 8) outp[1600 + tid] = tebd_s[ta_sh * 8 + tid];
}

extern "C" void kernel_launch(void* const* d_in, const int* in_sizes, int n_in,
                              void* d_out, int out_size, void* d_ws, size_t ws_size,
                              hipStream_t stream) {
    const float* rij   = (const float*)d_in[0];
    const void*  nmask = d_in[1];
    const int*   atype = (const int*)d_in[2];
    const int*   ntype = (const int*)d_in[3];
    const float* tebd  = (const float*)d_in[4];
    const float* ew0 = (const float*)d_in[5];
    const float* eb0 = (const float*)d_in[6];
    const float* ew1 = (const float*)d_in[7];
    const float* eb1 = (const float*)d_in[8];
    const float* ew2 = (const float*)d_in[9];
    const float* eb2 = (const float*)d_in[10];
    const float* wq = (const float*)d_in[11];
    const float* bq = (const float*)d_in[12];
    const float* wk = (const float*)d_in[13];
    const float* bk = (const float*)d_in[14];
    const float* wv = (const float*)d_in[15];
    const float* bv = (const float*)d_in[16];
    const float* wo = (const float*)d_in[17];
    const float* bo = (const float*)d_in[18];
    const float* lng = (const float*)d_in[19];
    const float* lnb = (const float*)d_in[20];
    float* out = (float*)d_out;
    int* flag = (int*)d_ws;
    unsigned short* wsb = (unsigned short*)((char*)d_ws + 256);

    detect_mask_kernel<<<1, 64, 0, stream>>>((const unsigned char*)nmask, flag);
    prep_weights<<<276, 64, 0, stream>>>(wq, wk, wv, wo, ew2, ew0, ew1, wsb);
    dpa1_kernel<<<4096, 1024, 0, stream>>>(rij, nmask, atype, ntype, tebd,
                                           eb0, eb1, eb2,
                                           bq, bk, bv, bo, lng, lnb,
                                           out, flag, wsb);
}

// Round 19
// 640.229 us; speedup vs baseline: 1.2616x; 1.0562x over previous
//
#include <hip/hip_runtime.h>

// DescrptDPA1 on gfx950 — R19: R18 + pair-local core syncs. O' relocated
// kn_s->buf1 so B2..B5 (+ new P~->O' handoff) protect only pair-owned rows;
// they become 5 LDS-counter pair syncs. Global barriers 6->2 per layer;
// the 8 wave-pairs pipeline through the core phases independently.
// NF=1, NLOC=4096, NNEI=120, TEBD=8, NTYPES=4, M=100, ATTN=128, NLAYER=2, AXIS=16.

#define NNEI 120
#define MDIM 100
#define ADIM 128
#define BP   136   // bf16 pitch (272B rows; 68 dw = 4 mod 32 banks, 16B aligned)
#define H2P  72    // bf16 pitch for h2 staging
#define XP   40    // bf16 pitch for x / h1 staging (80B rows, 16B aligned)
#define RHP  40    // bf16 pitch for rhat staging
#define OUTD 1608

typedef __attribute__((ext_vector_type(8))) short bf16x8;
typedef __attribute__((ext_vector_type(4))) float f32x4;

__device__ __forceinline__ float bf2f(unsigned short u){
    return __uint_as_float(((unsigned int)u) << 16);
}
__device__ __forceinline__ unsigned short f2bf(float f){
    unsigned int x = __float_as_uint(f);
    return (unsigned short)((x + 0x7fffu + ((x >> 16) & 1u)) >> 16);
}
__device__ __forceinline__ unsigned int cvtpk(float lo, float hi){
    unsigned int r;
    asm("v_cvt_pk_bf16_f32 %0, %1, %2" : "=v"(r) : "v"(lo), "v"(hi));
    return r;
}
__device__ __forceinline__ float ftanh(float x){
    return 1.0f - 2.0f / (__expf(2.0f * x) + 1.0f);
}
__device__ __forceinline__ float red16(float v){
    v += __shfl_xor(v, 1, 64); v += __shfl_xor(v, 2, 64);
    v += __shfl_xor(v, 4, 64); v += __shfl_xor(v, 8, 64);
    return v;
}

// nmask storage detection: 1 = int32 {0,1}, 2 = f32 {0.0,1.0}, 0 = byte bool
__global__ void detect_mask_kernel(const unsigned char* __restrict__ p,
                                   int* __restrict__ flag){
    if (blockIdx.x == 0 && threadIdx.x == 0){
        const unsigned int* u = (const unsigned int*)p;
        int alli = 1, allf = 1;
        for (int i = 0; i < 64; ++i){
            unsigned int w = u[i];
            if (!(w == 0u || w == 1u)) alli = 0;
            if (!(w == 0u || w == 0x3f800000u)) allf = 0;
        }
        flag[0] = alli ? 1 : (allf ? 2 : 0);
    }
}

// Pack weights (bf16). Frag = [64 lanes][8 bf16] = 1024B.
// QKV B-frags: fid = ((l*3+mat)*8+nt)*4+ks            (0..191)
// WO A-frags:  fid = 192 + (l*8+jt)*4+ks              (192..255, jt=7 zero)
// ew2 B-frags: fid = 256 + nt*2 + ks                  (256..269)
// ew0 B-frags: fid = 270 + nt   (nt=0,1; K=17 pad 32) (270..271)
// ew1 B-frags: fid = 272 + nt   (nt=0..3; K=25 pad 32)(272..275)
__global__ void prep_weights(const float* __restrict__ wq, const float* __restrict__ wk,
                             const float* __restrict__ wv, const float* __restrict__ wo,
                             const float* __restrict__ ew2, const float* __restrict__ ew0,
                             const float* __restrict__ ew1,
                             unsigned short* __restrict__ wsb){
    const int fid = blockIdx.x;
    const int lane = threadIdx.x;  // 64
    unsigned short* dst = wsb + (size_t)fid * 512 + lane * 8;
    if (fid < 192){
        const int l = fid / 96, rem = fid % 96, mat = rem / 32;
        const int r2 = rem % 32, nt = r2 / 4, ks = r2 % 4;
        const float* W = (mat == 0 ? wq : mat == 1 ? wk : wv) + l * MDIM * ADIM;
        const int nn = nt * 16 + (lane & 15);
        const int k0 = ks * 32 + (lane >> 4) * 8;
        #pragma unroll
        for (int i = 0; i < 8; ++i){
            const int kk = k0 + i;
            dst[i] = (kk < MDIM) ? f2bf(W[kk * ADIM + nn]) : (unsigned short)0;
        }
    } else if (fid < 256){
        const int f2 = fid - 192, l = f2 / 32, rem = f2 % 32, jt = rem / 4, ks = rem % 4;
        const float* W = wo + l * ADIM * MDIM;
        const int j = jt * 16 + (lane & 15);
        const int d0 = ks * 32 + (lane >> 4) * 8;
        #pragma unroll
        for (int i = 0; i < 8; ++i)
            dst[i] = (j < MDIM) ? f2bf(W[(d0 + i) * MDIM + j]) : (unsigned short)0;
    } else if (fid < 270){
        const int f3 = fid - 256, nt = f3 >> 1, ks = f3 & 1;
        const int nn = nt * 16 + (lane & 15);
        const int k0 = ks * 32 + (lane >> 4) * 8;
        #pragma unroll
        for (int i = 0; i < 8; ++i){
            const int kk = k0 + i;
            dst[i] = (kk < 50 && nn < MDIM) ? f2bf(ew2[kk * MDIM + nn]) : (unsigned short)0;
        }
    } else if (fid < 272){
        const int nt = fid - 270;
        const int nn = nt * 16 + (lane & 15);
        const int k0 = (lane >> 4) * 8;
        #pragma unroll
        for (int i = 0; i < 8; ++i){
            const int kk = k0 + i;
            dst[i] = (kk < 17 && nn < 25) ? f2bf(ew0[kk * 25 + nn]) : (unsigned short)0;
        }
    } else {
        const int nt = fid - 272;
        const int nn = nt * 16 + (lane & 15);
        const int k0 = (lane >> 4) * 8;
        #pragma unroll
        for (int i = 0; i < 8; ++i){
            const int kk = k0 + i;
            dst[i] = (kk < 25 && nn < 50) ? f2bf(ew1[kk * 50 + nn]) : (unsigned short)0;
        }
    }
}

__global__ __launch_bounds__(1024) void dpa1_kernel(
    const float* __restrict__ rij, const void* __restrict__ nmask,
    const int* __restrict__ atype, const int* __restrict__ ntype,
    const float* __restrict__ tebd,
    const float* __restrict__ eb0, const float* __restrict__ eb1,
    const float* __restrict__ eb2,
    const float* __restrict__ bq, const float* __restrict__ bk,
    const float* __restrict__ bv, const float* __restrict__ bo,
    const float* __restrict__ lng, const float* __restrict__ lnb,
    float* __restrict__ out, const int* __restrict__ flagp,
    const unsigned short* __restrict__ wsb)
{
    __shared__ __align__(16) unsigned short g16[128 * BP];   // bf16 g master
    __shared__ __align__(16) unsigned short buf1[128 * BP];  // h2 -> Qraw -> P~ -> O' -> envT
    __shared__ __align__(16) unsigned short kn_s[128 * BP];  // x -> Kraw
    __shared__ __align__(16) unsigned short vT_s[128 * BP];  // h1 -> Vraw^T
    __shared__ __align__(16) unsigned short rh16[128 * RHP]; // bf16 rhat (K=32 zero-pad)
    __shared__ float psum_s[256];
    __shared__ float lnp_s[512];
    __shared__ float qss2_s[256];         // |Q row|^2 per (half, row)
    __shared__ __align__(16) float kss_s[128];  // tinv * rsqrt(|K row|^2)
    __shared__ __align__(16) float vss_s[128];  // swm_k * rsqrt(|V row|^2)
    __shared__ __align__(16) float env_s[128 * 4];
    __shared__ __align__(16) float swm_s[128];
    __shared__ __align__(16) float msk_s[128];
    __shared__ float tebd_s[32];
    __shared__ float gr_s[4 * MDIM];
    __shared__ int   pairsync[8];
    __shared__ int ta_sh;

    const int n    = blockIdx.x;
    const int tid  = threadIdx.x;
    const int lane = tid & 63;
    const int wid  = tid >> 6;
    const int flag = flagp[0];
    const int l15  = lane & 15;
    const int lg4  = lane >> 4;
    const int qt   = wid >> 1;   // pair id / q-tile
    const int hh   = wid & 1;    // half index within pair
    const int q    = qt * 16 + l15;

    if (tid < 32) tebd_s[tid] = tebd[tid];
    if (tid == 0) ta_sh = atype[n];
    if (tid < 8)  pairsync[tid] = 0;

    // pair-local sync: both waves of pair qt arrive; monotone generation counter
    #define PAIR_SYNC(gen_) do {                                              \
        asm volatile("s_waitcnt lgkmcnt(0)" ::: "memory");                    \
        __builtin_amdgcn_sched_barrier(0);                                    \
        if (lane == 0) atomicAdd(&pairsync[qt], 1);                           \
        volatile int* pf_ = (volatile int*)&pairsync[qt];                     \
        while (*pf_ < 2 * (gen_)) __builtin_amdgcn_s_sleep(1);                \
        __builtin_amdgcn_sched_barrier(0);                                    \
    } while (0)

    // ---------------- P-geom: geometry + x/rhat staging + zero g16 -----------
    {
        unsigned int* z0 = (unsigned int*)g16;
        for (int i = tid; i < 128 * (BP/2); i += 1024) z0[i] = 0;
    }
    if (tid < 128){
        const int k = tid;
        unsigned short xr[2 * XP];
        #pragma unroll
        for (int i = 0; i < 2 * XP; ++i) xr[i] = 0;
        unsigned short rr[32];
        #pragma unroll
        for (int i = 0; i < 32; ++i) rr[i] = 0;
        if (k < NNEI){
            const int base = n * NNEI + k;
            const float rx = rij[base * 3 + 0];
            const float ry = rij[base * 3 + 1];
            const float rz = rij[base * 3 + 2];
            const float r  = sqrtf(rx * rx + ry * ry + rz * rz);
            float mval;
            if (flag == 1)      mval = (((const int*)nmask)[base] != 0) ? 1.0f : 0.0f;
            else if (flag == 2) mval = ((const float*)nmask)[base];
            else                mval = (((const unsigned char*)nmask)[base] != 0) ? 1.0f : 0.0f;
            float uu = (r - 0.5f) * (1.0f / 5.5f);
            uu = fminf(fmaxf(uu, 0.0f), 1.0f);
            const float sw   = uu * uu * uu * (-6.0f * uu * uu + 15.0f * uu - 10.0f) + 1.0f;
            const float invr = 1.0f / r;
            const float sr   = sw * invr * mval;
            const float hx = rx * invr, hy = ry * invr, hz = rz * invr;
            env_s[k * 4 + 0] = sr;
            env_s[k * 4 + 1] = sr * hx;
            env_s[k * 4 + 2] = sr * hy;
            env_s[k * 4 + 3] = sr * hz;
            swm_s[k] = sw * mval;
            msk_s[k] = mval;
            const int tn = ntype[base] * 8;
            const int tc = atype[n] * 8;
            xr[0] = f2bf(sr);
            #pragma unroll
            for (int i = 0; i < 8; ++i){
                xr[1 + i] = f2bf(tebd[tn + i]);
                xr[9 + i] = f2bf(tebd[tc + i]);
            }
            rr[0] = f2bf(hx); rr[1] = f2bf(hy); rr[2] = f2bf(hz);
        } else {
            env_s[k*4+0] = env_s[k*4+1] = env_s[k*4+2] = env_s[k*4+3] = 0.0f;
            swm_s[k] = 0.0f; msk_s[k] = 0.0f;
        }
        #pragma unroll
        for (int c = 0; c < 5; ++c)
            *(uint4*)&kn_s[k * XP + c * 8] = *(const uint4*)&xr[c * 8];
        #pragma unroll
        for (int c = 0; c < 4; ++c)
            *(uint4*)&rh16[k * RHP + c * 8] = *(const uint4*)&rr[c * 8];
    }
    __syncthreads();

    // ---------------- e1 (MFMA): h1 = tanh(x @ ew0 + eb0) -> vT_s bf16 -------
    {
        const int mt = wid >> 1, nt = wid & 1;   // 16 jobs, 1 per wave
        bf16x8 a = *(const bf16x8*)&kn_s[(mt*16 + l15) * XP + lg4 * 8];
        bf16x8 b = *(const bf16x8*)(wsb + (size_t)(270 + nt) * 512 + lane * 8);
        f32x4 C = (f32x4){0.f, 0.f, 0.f, 0.f};
        C = __builtin_amdgcn_mfma_f32_16x16x32_bf16(a, b, C, 0, 0, 0);
        const int j = nt * 16 + l15;
        const float ebj = (j < 25) ? eb0[j] : 0.0f;
        #pragma unroll
        for (int r = 0; r < 4; ++r){
            const int row = mt * 16 + lg4 * 4 + r;
            const float v = (row < NNEI && j < 25) ? ftanh(C[r] + ebj) : 0.0f;
            vT_s[row * XP + j] = f2bf(v);
        }
    }
    __syncthreads();

    // ---------------- e2 (MFMA): h2 = tanh(h1 @ ew1 + eb1) + [h1,h1] -> buf1 --
    {
        for (int jb = wid; jb < 32; jb += 16){   // 2 jobs per wave
            const int mt = jb >> 2, nt = jb & 3;
            bf16x8 a = *(const bf16x8*)&vT_s[(mt*16 + l15) * XP + lg4 * 8];
            bf16x8 b = *(const bf16x8*)(wsb + (size_t)(272 + nt) * 512 + lane * 8);
            f32x4 C = (f32x4){0.f, 0.f, 0.f, 0.f};
            C = __builtin_amdgcn_mfma_f32_16x16x32_bf16(a, b, C, 0, 0, 0);
            const int j2 = nt * 16 + l15;
            const float ebj = (j2 < 50) ? eb1[j2] : 0.0f;
            const int jr = (j2 >= 25) ? j2 - 25 : j2;
            #pragma unroll
            for (int r = 0; r < 4; ++r){
                const int row = mt * 16 + lg4 * 4 + r;
                float v = 0.0f;
                if (row < NNEI && j2 < 50){
                    const float h1d = bf2f(vT_s[row * XP + jr]);
                    v = ftanh(C[r] + ebj) + h1d;
                }
                buf1[row * H2P + j2] = f2bf(v);
            }
        }
    }
    __syncthreads();

    // ---------------- e3: g = (tanh(h2 @ ew2 + eb2) + [h2,h2]) * m  (MFMA) ---
    {
        for (int job = wid; job < 56; job += 16){
            const int mt = job / 7, nt = job - mt * 7;
            bf16x8 a0 = *(const bf16x8*)&buf1[(mt*16 + l15) * H2P + 0*32 + lg4 * 8];
            bf16x8 a1 = *(const bf16x8*)&buf1[(mt*16 + l15) * H2P + 1*32 + lg4 * 8];
            bf16x8 b0 = *(const bf16x8*)(wsb + (size_t)(256 + nt*2 + 0) * 512 + lane * 8);
            bf16x8 b1 = *(const bf16x8*)(wsb + (size_t)(256 + nt*2 + 1) * 512 + lane * 8);
            f32x4 C = (f32x4){0.f, 0.f, 0.f, 0.f};
            C = __builtin_amdgcn_mfma_f32_16x16x32_bf16(a0, b0, C, 0, 0, 0);
            C = __builtin_amdgcn_mfma_f32_16x16x32_bf16(a1, b1, C, 0, 0, 0);
            const int j = nt * 16 + l15;
            if (j < MDIM){
                const float ebj = eb2[j];
                const int jr = (j >= 50) ? j - 50 : j;
                #pragma unroll
                for (int r = 0; r < 4; ++r){
                    const int row = mt * 16 + lg4 * 4 + r;
                    if (row < NNEI){
                        const float h2d = bf2f(buf1[row * H2P + jr]);
                        const float t = ftanh(C[r] + ebj) + h2d;
                        g16[row * BP + j] = f2bf(t * msk_s[row]);
                    }
                }
            }
        }
    }
    __syncthreads();

    // ---------------- Attention layers ----------------
    const float tinv = 0.08838834764831845f;  // 1/sqrt(128)

    for (int l = 0; l < 2; ++l){
        // ===== A1 (balanced, raw store): each wave = 1 full K-or-V job
        //       (store raw, publish scale) + 1 half raw-Q job (same tile) ====
        {
            const int t = wid & 7;
            bf16x8 ag[4];
            #pragma unroll
            for (int ks = 0; ks < 4; ++ks)
                ag[ks] = *(const bf16x8*)&g16[(t*16 + l15) * BP + ks*32 + lg4 * 8];
            if (wid < 8){
                // K tile t: store raw K; publish kss = tinv*rsqrt(rowsum)
                float sq[4] = {0.f, 0.f, 0.f, 0.f};
                #pragma unroll
                for (int nt = 0; nt < 8; ++nt){
                    f32x4 C = (f32x4){0.f, 0.f, 0.f, 0.f};
                    #pragma unroll
                    for (int ks = 0; ks < 4; ++ks){
                        bf16x8 b = *(const bf16x8*)(wsb + (size_t)(((l*3+1)*8+nt)*4+ks) * 512 + lane * 8);
                        C = __builtin_amdgcn_mfma_f32_16x16x32_bf16(ag[ks], b, C, 0, 0, 0);
                    }
                    const float bias = bk[l * ADIM + nt*16 + l15];
                    #pragma unroll
                    for (int r = 0; r < 4; ++r){
                        const float v = C[r] + bias;
                        kn_s[(t*16 + lg4*4 + r) * BP + nt*16 + l15] = f2bf(v);
                        sq[r] = fmaf(v, v, sq[r]);
                    }
                }
                #pragma unroll
                for (int r = 0; r < 4; ++r){
                    const float s = red16(sq[r]);
                    if (l15 == 0) kss_s[t*16 + lg4*4 + r] = tinv * rsqrtf(fmaxf(s, 1e-24f));
                }
            } else {
                // V tile t: store raw V^T; publish vss = swm_k*rsqrt(rowsum)
                float sq[4] = {0.f, 0.f, 0.f, 0.f};
                #pragma unroll
                for (int nt = 0; nt < 8; ++nt){
                    f32x4 C = (f32x4){0.f, 0.f, 0.f, 0.f};
                    #pragma unroll
                    for (int ks = 0; ks < 4; ++ks){
                        bf16x8 b = *(const bf16x8*)(wsb + (size_t)(((l*3+2)*8+nt)*4+ks) * 512 + lane * 8);
                        C = __builtin_amdgcn_mfma_f32_16x16x32_bf16(ag[ks], b, C, 0, 0, 0);
                    }
                    const float bias = bv[l * ADIM + nt*16 + l15];
                    float v0 = C[0] + bias, v1 = C[1] + bias;
                    float v2 = C[2] + bias, v3 = C[3] + bias;
                    sq[0] = fmaf(v0, v0, sq[0]); sq[1] = fmaf(v1, v1, sq[1]);
                    sq[2] = fmaf(v2, v2, sq[2]); sq[3] = fmaf(v3, v3, sq[3]);
                    *(uint2*)&vT_s[(nt*16 + l15) * BP + t*16 + lg4*4] =
                        make_uint2(cvtpk(v0, v1), cvtpk(v2, v3));
                }
                #pragma unroll
                for (int r = 0; r < 4; ++r){
                    const int k = t*16 + lg4*4 + r;
                    const float s = red16(sq[r]);
                    if (l15 == 0) vss_s[k] = swm_s[k] * rsqrtf(fmaxf(s, 1e-24f));
                }
            }
            __builtin_amdgcn_sched_barrier(0);
            // Half-width raw-Q job on the SAME tile t, half hq = wid>>3
            {
                const int hq = wid >> 3;
                float sq2[4] = {0.f, 0.f, 0.f, 0.f};
                #pragma unroll
                for (int u = 0; u < 4; ++u){
                    const int nt = hq*4 + u;
                    f32x4 C = (f32x4){0.f, 0.f, 0.f, 0.f};
                    #pragma unroll
                    for (int ks = 0; ks < 4; ++ks){
                        bf16x8 b = *(const bf16x8*)(wsb + (size_t)(((l*3+0)*8+nt)*4+ks) * 512 + lane * 8);
                        C = __builtin_amdgcn_mfma_f32_16x16x32_bf16(ag[ks], b, C, 0, 0, 0);
                    }
                    const float bias = bq[l * ADIM + nt*16 + l15];
                    #pragma unroll
                    for (int r = 0; r < 4; ++r){
                        const float v = C[r] + bias;
                        buf1[(t*16 + lg4*4 + r) * BP + nt*16 + l15] = f2bf(v);
                        sq2[r] = fmaf(v, v, sq2[r]);
                    }
                }
                #pragma unroll
                for (int r = 0; r < 4; ++r){
                    const float s = red16(sq2[r]);
                    if (l15 == 0) qss2_s[hq * 128 + t*16 + lg4*4 + r] = s;
                }
            }
        }
        __syncthreads();  // B1 (global): Qraw, Kraw, Vraw^T, qss/kss/vss ready

        // ===== Core1: scores half + gate via MFMA; consumer-side scales ======
        unsigned int pw0[4], pw1[4];
        float tot;
        {
            bf16x8 bqf[4];
            #pragma unroll
            for (int ks = 0; ks < 4; ++ks)
                bqf[ks] = *(const bf16x8*)&buf1[(qt*16 + l15) * BP + ks*32 + lg4 * 8];
            bf16x8 bgq = *(const bf16x8*)&rh16[(qt*16 + l15) * RHP + lg4 * 8];
            f32x4 Cs[4];
            #pragma unroll
            for (int t = 0; t < 4; ++t) Cs[t] = (f32x4){0.f, 0.f, 0.f, 0.f};
            #pragma unroll
            for (int t = 0; t < 4; ++t)
                #pragma unroll
                for (int ks = 0; ks < 4; ++ks){
                    bf16x8 a = *(const bf16x8*)&kn_s[((hh*4+t)*16 + l15) * BP + ks*32 + lg4 * 8];
                    Cs[t] = __builtin_amdgcn_mfma_f32_16x16x32_bf16(a, bqf[ks], Cs[t], 0, 0, 0);
                }
            const float qi = rsqrtf(fmaxf(qss2_s[q] + qss2_s[128 + q], 1e-24f));
            tot = 0.f;
            #pragma unroll
            for (int t = 0; t < 4; ++t){
                const int kb = (hh*4+t)*16 + lg4*4;
                bf16x8 agk = *(const bf16x8*)&rh16[((hh*4+t)*16 + l15) * RHP + lg4 * 8];
                f32x4 G = (f32x4){0.f, 0.f, 0.f, 0.f};
                G = __builtin_amdgcn_mfma_f32_16x16x32_bf16(agk, bgq, G, 0, 0, 0);
                const float4 ks4 = *(const float4*)&kss_s[kb];
                const float4 vs4 = *(const float4*)&vss_s[kb];
                float p[4];
                #pragma unroll
                for (int r = 0; r < 4; ++r){
                    const float e = __expf(Cs[t][r] * qi * ((const float*)&ks4)[r]) * msk_s[kb + r];
                    tot += e;
                    p[r] = e * G[r] * ((const float*)&vs4)[r];
                }
                pw0[t] = cvtpk(p[0], p[1]);
                pw1[t] = cvtpk(p[2], p[3]);
            }
            tot += __shfl_xor(tot, 16, 64);
            tot += __shfl_xor(tot, 32, 64);
        }
        PAIR_SYNC(l * 5 + 1);  // S1: pair done reading buf1 Q rows

        // ===== Core2: publish P~ (= e*gate*vss) and psum (pair-local) =====
        #pragma unroll
        for (int t = 0; t < 4; ++t)
            *(uint2*)&buf1[(qt*16 + l15) * BP + (hh*4+t)*16 + lg4*4] = make_uint2(pw0[t], pw1[t]);
        if (lg4 == 0) psum_s[q * 2 + hh] = tot;
        PAIR_SYNC(l * 5 + 2);  // S2: P~, psum visible to pair

        // ===== Core3: PV half; apply rsum to Co (regs) =====
        f32x4 Co[4];
        {
            bf16x8 bpf[4];
            #pragma unroll
            for (int ks = 0; ks < 4; ++ks)
                bpf[ks] = *(const bf16x8*)&buf1[(qt*16 + l15) * BP + ks*32 + lg4 * 8];
            #pragma unroll
            for (int t = 0; t < 4; ++t) Co[t] = (f32x4){0.f, 0.f, 0.f, 0.f};
            #pragma unroll
            for (int t = 0; t < 4; ++t)
                #pragma unroll
                for (int ks = 0; ks < 4; ++ks){
                    bf16x8 a = *(const bf16x8*)&vT_s[((hh*4+t)*16 + l15) * BP + ks*32 + lg4 * 8];
                    Co[t] = __builtin_amdgcn_mfma_f32_16x16x32_bf16(a, bpf[ks], Co[t], 0, 0, 0);
                }
        }
        PAIR_SYNC(l * 5 + 3);  // S3: pair done reading P~ rows
        {
            const float totq = psum_s[q * 2] + psum_s[q * 2 + 1];
            const float rsum = (totq > 0.0f) ? swm_s[q] / totq : 0.0f;
            #pragma unroll
            for (int t = 0; t < 4; ++t){
                const unsigned int lo = cvtpk(Co[t][0] * rsum, Co[t][1] * rsum);
                const unsigned int hi = cvtpk(Co[t][2] * rsum, Co[t][3] * rsum);
                *(uint2*)&buf1[(qt*16 + l15) * BP + (hh*4+t)*16 + lg4*4] = make_uint2(lo, hi);
            }
        }
        PAIR_SYNC(l * 5 + 4);  // S4: O' visible to pair

        // ===== Core4: out-proj half + LN partials =====
        float val[4][4];
        {
            bf16x8 bof[4];
            #pragma unroll
            for (int ks = 0; ks < 4; ++ks)
                bof[ks] = *(const bf16x8*)&buf1[(qt*16 + l15) * BP + ks*32 + lg4 * 8];
            const float* BO = bo + l * MDIM;
            float sv = 0.f, sv2 = 0.f;
            #pragma unroll
            for (int t = 0; t < 4; ++t){
                const int jt = hh*4 + t;
                f32x4 Cf = (f32x4){0.f, 0.f, 0.f, 0.f};
                #pragma unroll
                for (int ks = 0; ks < 4; ++ks){
                    bf16x8 a = *(const bf16x8*)(wsb + (size_t)(192 + (l*8+jt)*4 + ks) * 512 + lane * 8);
                    Cf = __builtin_amdgcn_mfma_f32_16x16x32_bf16(a, bof[ks], Cf, 0, 0, 0);
                }
                const bool jok = (jt < 6) || (jt == 6 && lg4 == 0);
                float4 BO4 = jok ? *(const float4*)&BO[jt*16 + lg4*4] : make_float4(0,0,0,0);
                #pragma unroll
                for (int r = 0; r < 4; ++r){
                    const float v = Cf[r] + ((const float*)&BO4)[r];
                    val[t][r] = v;
                    if (jok){ sv += v; sv2 += v * v; }
                }
            }
            sv  += __shfl_xor(sv, 16, 64);  sv  += __shfl_xor(sv, 32, 64);
            sv2 += __shfl_xor(sv2, 16, 64); sv2 += __shfl_xor(sv2, 32, 64);
            if (lg4 == 0){
                lnp_s[q * 4 + hh * 2 + 0] = sv;
                lnp_s[q * 4 + hh * 2 + 1] = sv2;
            }
        }
        PAIR_SYNC(l * 5 + 5);  // S5: LN partials visible to pair

        // ===== Core5: LayerNorm apply + residual into g16 (own jt half) =====
        {
            const float* LG = lng + l * MDIM;
            const float* LB = lnb + l * MDIM;
            const float svt  = lnp_s[q * 4 + 0] + lnp_s[q * 4 + 2];
            const float sv2t = lnp_s[q * 4 + 1] + lnp_s[q * 4 + 3];
            const float mu   = svt * 0.01f;
            const float var  = sv2t * 0.01f - mu * mu;
            const float rstd = rsqrtf(var + 1e-5f);
            if (q < NNEI){
                #pragma unroll
                for (int t = 0; t < 4; ++t){
                    const int jt = hh*4 + t;
                    const bool jok = (jt < 6) || (jt == 6 && lg4 == 0);
                    if (jok){
                        const int jb = jt*16 + lg4*4;
                        const float4 LG4 = *(const float4*)&LG[jb];
                        const float4 LB4 = *(const float4*)&LB[jb];
                        uint2 old = *(const uint2*)&g16[q * BP + jb];
                        float nv[4];
                        nv[0] = bf2f((unsigned short)(old.x & 0xffffu))  + (val[t][0] - mu) * rstd * LG4.x + LB4.x;
                        nv[1] = bf2f((unsigned short)(old.x >> 16))      + (val[t][1] - mu) * rstd * LG4.y + LB4.y;
                        nv[2] = bf2f((unsigned short)(old.y & 0xffffu))  + (val[t][2] - mu) * rstd * LG4.z + LB4.z;
                        nv[3] = bf2f((unsigned short)(old.y >> 16))      + (val[t][3] - mu) * rstd * LG4.w + LB4.w;
                        uint2 nw;
                        nw.x = cvtpk(nv[0], nv[1]);
                        nw.y = cvtpk(nv[2], nv[3]);
                        *(uint2*)&g16[q * BP + jb] = nw;
                    }
                }
            }
        }
        __syncthreads();  // B6 (global): end of layer
    }

    // ---------------- Final: gr = env^T g / NNEI (MFMA) ; d = gr^T gr[:,:16] --
    for (int idx = tid; idx < 16 * 128; idx += 1024){
        const int c = idx >> 7, k = idx & 127;
        buf1[c * BP + k] = (c < 4) ? f2bf(env_s[k * 4 + c]) : (unsigned short)0;
    }
    __syncthreads();
    if (wid < 7){
        const int nt = wid;
        bf16x8 ae[4];
        #pragma unroll
        for (int ks = 0; ks < 4; ++ks)
            ae[ks] = *(const bf16x8*)&buf1[l15 * BP + ks*32 + lg4 * 8];
        f32x4 C = (f32x4){0.f, 0.f, 0.f, 0.f};
        #pragma unroll
        for (int ks = 0; ks < 4; ++ks){
            unsigned short bw[8];
            #pragma unroll
            for (int i = 0; i < 8; ++i)
                bw[i] = g16[(ks*32 + lg4*8 + i) * BP + nt*16 + l15];
            bf16x8 b = *(const bf16x8*)bw;
            C = __builtin_amdgcn_mfma_f32_16x16x32_bf16(ae[ks], b, C, 0, 0, 0);
        }
        const int m = nt * 16 + l15;
        if (lg4 == 0 && m < MDIM){
            #pragma unroll
            for (int r = 0; r < 4; ++r)
                gr_s[r * MDIM + m] = C[r] * (1.0f / 120.0f);
        }
    }
    __syncthreads();

    float* outp = out + (size_t)n * OUTD;
    for (int idx = tid; idx < MDIM * 16; idx += 1024){
        const int mm = idx >> 4, aa = idx & 15;
        float acc = 0.0f;
        #pragma unroll
        for (int c = 0; c < 4; ++c)
            acc = fmaf(gr_s[c * MDIM + mm], gr_s[c * MDIM + aa], acc);
        outp[idx] = acc;
    }
    if (tid < 8) outp[1600 + tid] = tebd_s[ta_sh * 8 + tid];
    #undef PAIR_SYNC
}

extern "C" void kernel_launch(void* const* d_in, const int* in_sizes, int n_in,
                              void* d_out, int out_size, void* d_ws, size_t ws_size,
                              hipStream_t stream) {
    const float* rij   = (const float*)d_in[0];
    const void*  nmask = d_in[1];
    const int*   atype = (const int*)d_in[2];
    const int*   ntype = (const int*)d_in[3];
    const float* tebd  = (const float*)d_in[4];
    const float* ew0 = (const float*)d_in[5];
    const float* eb0 = (const float*)d_in[6];
    const float* ew1 = (const float*)d_in[7];
    const float* eb1 = (const float*)d_in[8];
    const float* ew2 = (const float*)d_in[9];
    const float* eb2 = (const float*)d_in[10];
    const float* wq = (const float*)d_in[11];
    const float* bq = (const float*)d_in[12];
    const float* wk = (const float*)d_in[13];
    const float* bk = (const float*)d_in[14];
    const float* wv = (const float*)d_in[15];
    const float* bv = (const float*)d_in[16];
    const float* wo = (const float*)d_in[17];
    const float* bo = (const float*)d_in[18];
    const float* lng = (const float*)d_in[19];
    const float* lnb = (const float*)d_in[20];
    float* out = (float*)d_out;
    int* flag = (int*)d_ws;
    unsigned short* wsb = (unsigned short*)((char*)d_ws + 256);

    detect_mask_kernel<<<1, 64, 0, stream>>>((const unsigned char*)nmask, flag);
    prep_weights<<<276, 64, 0, stream>>>(wq, wk, wv, wo, ew2, ew0, ew1, wsb);
    dpa1_kernel<<<4096, 1024, 0, stream>>>(rij, nmask, atype, ntype, tebd,
                                           eb0, eb1, eb2,
                                           bq, bk, bv, bo, lng, lnb,
                                           out, flag, wsb);
}